// Round 1
// baseline (3153.485 us; speedup 1.0000x reference)
//
#include <hip/hip_runtime.h>
#include <hip/hip_bf16.h>
#include <math.h>

#define HH 160
#define WW 160
#define HWsz (HH*WW)
#define TS 16
#define TP 18   // TS + 2 halo

// -------------------------------------------------------------------------
// Generic direct 3x3 SAME conv, fused bias + optional ReLU.
// Block: 256 threads = 16x16 pixel tile. Each block computes 16 output
// channels for its tile. Input channels staged to LDS in chunks of 16.
// CONCAT=true: input is feats(5,64,H,W); logical Cin=128 where channels
// 0..63 come from frame 2 (ref) and 64..127 from frame map(frame).
// -------------------------------------------------------------------------
template<bool RELU, bool CONCAT>
__global__ __launch_bounds__(256)
void conv3x3_kernel(const float* __restrict__ in,
                    const float* __restrict__ wgt,   // (Cout, Cin, 3, 3)
                    const float* __restrict__ bias,  // (Cout)
                    float* __restrict__ out,         // (frames, Cout, H, W)
                    int Cin, int Cout, int co_groups)
{
    const int tile_x = blockIdx.x, tile_y = blockIdx.y;
    const int frame  = blockIdx.z / co_groups;
    const int cog    = blockIdx.z % co_groups;
    const int co_base = cog * 16;

    __shared__ float s_in[16][TP][TP];
    __shared__ float s_w[16][16][9];   // [co][ci][tap]

    const int t  = threadIdx.x;
    const int tx = t & 15, ty = t >> 4;
    const int x0 = tile_x * TS, y0 = tile_y * TS;

    float acc[16];
#pragma unroll
    for (int i = 0; i < 16; ++i) acc[i] = 0.f;

    const int nchunks = (Cin + 15) >> 4;
    for (int ch = 0; ch < nchunks; ++ch) {
        const int ci0 = ch * 16;
        // ---- stage input chunk (zero-padded halo) ----
        for (int i = t; i < 16 * TP * TP; i += 256) {
            const int cc  = i / (TP * TP);
            const int rem = i % (TP * TP);
            const int yy  = rem / TP, xx = rem % TP;
            const int gy = y0 + yy - 1, gx = x0 + xx - 1;
            const int gc = ci0 + cc;
            float v = 0.f;
            if (gc < Cin && gy >= 0 && gy < HH && gx >= 0 && gx < WW) {
                const float* plane;
                if (CONCAT) {
                    const int fidx = (gc < 64) ? 2 : (frame < 2 ? frame : frame + 1);
                    plane = in + ((size_t)fidx * 64 + (gc & 63)) * HWsz;
                } else {
                    plane = in + ((size_t)frame * Cin + gc) * HWsz;
                }
                v = plane[gy * WW + gx];
            }
            s_in[cc][yy][xx] = v;
        }
        // ---- stage weights for this (co group, ci chunk) ----
        for (int i = t; i < 16 * 16 * 9; i += 256) {
            const int co  = i / (16 * 9);
            const int rem = i % (16 * 9);
            const int ci  = rem / 9, tap = rem % 9;
            const int gco = co_base + co, gci = ci0 + ci;
            float v = 0.f;
            if (gco < Cout && gci < Cin)
                v = wgt[((size_t)gco * Cin + gci) * 9 + tap];
            s_w[co][ci][tap] = v;
        }
        __syncthreads();
        // ---- compute ----
#pragma unroll 2
        for (int ci = 0; ci < 16; ++ci) {
#pragma unroll
            for (int tap = 0; tap < 9; ++tap) {
                const float v = s_in[ci][ty + tap / 3][tx + tap % 3];
#pragma unroll
                for (int co = 0; co < 16; ++co)
                    acc[co] = fmaf(v, s_w[co][ci][tap], acc[co]);
            }
        }
        __syncthreads();
    }
    // ---- store ----
    const int gy = y0 + ty, gx = x0 + tx;
#pragma unroll
    for (int co = 0; co < 16; ++co) {
        const int gco = co_base + co;
        if (gco < Cout) {
            float r = acc[co] + bias[gco];
            if (RELU) r = fmaxf(r, 0.f);
            out[((size_t)frame * Cout + gco) * HWsz + gy * WW + gx] = r;
        }
    }
}

// -------------------------------------------------------------------------
// Modulated deformable conv. Block: 256 threads = 16x16 pixel tile, one
// aligned frame per blockIdx.z. Each thread owns 1 pixel and all 64 output
// channel accumulators. Loop over deformable groups g: per-group weight
// slice (8 ci x 9 tap x 64 o) staged in LDS, read with uniform addresses
// (broadcast, conflict-free).
// -------------------------------------------------------------------------
__global__ __launch_bounds__(256)
void mdcn_kernel(const float* __restrict__ feats, // (5,64,H,W)
                 const float* __restrict__ raw,   // (4,216,H,W)
                 const float* __restrict__ dw,    // (64,64,3,3)
                 const float* __restrict__ db,    // (64)
                 float* __restrict__ out)         // (5,64,H,W)
{
    const int b    = blockIdx.z;              // 0..3 (aligned frame)
    const int fidx = (b < 2) ? b : b + 1;     // source/dest frame index

    const int t  = threadIdx.x;
    const int tx = t & 15, ty = t >> 4;
    const int w  = blockIdx.x * TS + tx;
    const int h  = blockIdx.y * TS + ty;
    const int hw = h * WW + w;

    __shared__ float s_w[8 * 9 * 64];   // [c][k][o]

    float acc[64];
#pragma unroll
    for (int i = 0; i < 64; ++i) acc[i] = 0.f;

    const float* rawb = raw + (size_t)b * 216 * HWsz;
    const float* xb   = feats + (size_t)fidx * 64 * HWsz;

    for (int g = 0; g < 8; ++g) {
        __syncthreads();
        for (int i = t; i < 8 * 9 * 64; i += 256) {
            const int c = i / (9 * 64);
            const int r = i % (9 * 64);
            const int k = r / 64, o = r % 64;
            s_w[i] = dw[((size_t)o * 64 + g * 8 + c) * 9 + k];
        }
        __syncthreads();

        for (int k = 0; k < 9; ++k) {
            const int kyy = k / 3 - 1, kxx = k % 3 - 1;
            const float oy = rawb[(size_t)(g * 18 + k * 2 + 0) * HWsz + hw];
            const float ox = rawb[(size_t)(g * 18 + k * 2 + 1) * HWsz + hw];
            float mval = rawb[(size_t)(144 + g * 9 + k) * HWsz + hw];
            mval = 1.f / (1.f + __expf(-mval));

            const float py = oy + (float)(h + kyy);
            const float px = ox + (float)(w + kxx);
            const float y0f = floorf(py), x0f = floorf(px);
            const float tyf = py - y0f, txf = px - x0f;
            const int y0 = (int)y0f, x0i = (int)x0f;
            const int y1 = y0 + 1, x1 = x0i + 1;
            const bool vy0 = (y0 >= 0) & (y0 < HH);
            const bool vy1 = (y1 >= 0) & (y1 < HH);
            const bool vx0 = (x0i >= 0) & (x0i < WW);
            const bool vx1 = (x1 >= 0) & (x1 < WW);
            const int yc0 = min(max(y0, 0), HH - 1), yc1 = min(max(y1, 0), HH - 1);
            const int xc0 = min(max(x0i, 0), WW - 1), xc1 = min(max(x1, 0), WW - 1);
            float w00 = (1.f - tyf) * (1.f - txf) * mval;
            float w01 = (1.f - tyf) * txf * mval;
            float w10 = tyf * (1.f - txf) * mval;
            float w11 = tyf * txf * mval;
            if (!(vy0 && vx0)) w00 = 0.f;
            if (!(vy0 && vx1)) w01 = 0.f;
            if (!(vy1 && vx0)) w10 = 0.f;
            if (!(vy1 && vx1)) w11 = 0.f;
            const int i00 = yc0 * WW + xc0, i01 = yc0 * WW + xc1;
            const int i10 = yc1 * WW + xc0, i11 = yc1 * WW + xc1;

#pragma unroll 2
            for (int c = 0; c < 8; ++c) {
                const float* xp = xb + (size_t)(g * 8 + c) * HWsz;
                const float v = w00 * xp[i00] + w01 * xp[i01]
                              + w10 * xp[i10] + w11 * xp[i11];
                const float* wl = &s_w[(c * 9 + k) * 64];
#pragma unroll
                for (int o = 0; o < 64; o += 4) {
                    const float4 w4 = *reinterpret_cast<const float4*>(wl + o);
                    acc[o + 0] = fmaf(v, w4.x, acc[o + 0]);
                    acc[o + 1] = fmaf(v, w4.y, acc[o + 1]);
                    acc[o + 2] = fmaf(v, w4.z, acc[o + 2]);
                    acc[o + 3] = fmaf(v, w4.w, acc[o + 3]);
                }
            }
        }
    }

    float* ob = out + (size_t)fidx * 64 * HWsz;
#pragma unroll
    for (int o = 0; o < 64; ++o)
        ob[(size_t)o * HWsz + hw] = acc[o] + db[o];
}

// Copy reference frame (feats frame 2) to output frame 2, float4.
__global__ __launch_bounds__(256)
void copy_ref_kernel(const float* __restrict__ feats, float* __restrict__ out)
{
    const size_t n = (size_t)64 * HWsz / 4;   // 409600 float4
    const size_t i = (size_t)blockIdx.x * 256 + threadIdx.x;
    if (i < n) {
        const float4* src = reinterpret_cast<const float4*>(feats + (size_t)2 * 64 * HWsz);
        float4* dst = reinterpret_cast<float4*>(out + (size_t)2 * 64 * HWsz);
        dst[i] = src[i];
    }
}

extern "C" void kernel_launch(void* const* d_in, const int* in_sizes, int n_in,
                              void* d_out, int out_size, void* d_ws, size_t ws_size,
                              hipStream_t stream)
{
    const float* x   = (const float*)d_in[0];   // (1,5,4,160,160)
    const float* fw1 = (const float*)d_in[1];
    const float* fb1 = (const float*)d_in[2];
    const float* fw2 = (const float*)d_in[3];
    const float* fb2 = (const float*)d_in[4];
    const float* fw3 = (const float*)d_in[5];
    const float* fb3 = (const float*)d_in[6];
    const float* ow1 = (const float*)d_in[7];
    const float* ob1 = (const float*)d_in[8];
    const float* ow2 = (const float*)d_in[9];
    const float* ob2 = (const float*)d_in[10];
    const float* ow3 = (const float*)d_in[11];
    const float* ob3 = (const float*)d_in[12];
    const float* dw  = (const float*)d_in[13];
    const float* db  = (const float*)d_in[14];
    float* out = (float*)d_out;

    float* ws    = (float*)d_ws;
    float* feats = ws;                       // 5*64*HW = 8,192,000 f
    float* buf1  = feats + (size_t)8192000;  // 8,192,000 f
    float* buf2  = buf1 + (size_t)8192000;   // 8,192,000 f
    float* raw   = buf2 + (size_t)8192000;   // 4*216*HW = 22,118,400 f

    const dim3 blk(256);

    // Feature extraction: 3x conv3x3+ReLU on 5 frames.
    conv3x3_kernel<true,  false><<<dim3(10, 10, 5 * 4),  blk, 0, stream>>>(x,    fw1, fb1, buf1, 4,   64,  4);
    conv3x3_kernel<true,  false><<<dim3(10, 10, 5 * 4),  blk, 0, stream>>>(buf1, fw2, fb2, buf2, 64,  64,  4);
    conv3x3_kernel<true,  false><<<dim3(10, 10, 5 * 4),  blk, 0, stream>>>(buf2, fw3, fb3, feats, 64, 64,  4);

    // Reference frame passthrough.
    copy_ref_kernel<<<dim3(1600), blk, 0, stream>>>(feats, out);

    // Offset network on concat(ref, curr) for 4 non-center frames.
    conv3x3_kernel<true,  true ><<<dim3(10, 10, 4 * 4),  blk, 0, stream>>>(feats, ow1, ob1, buf1, 128, 64,  4);
    conv3x3_kernel<true,  false><<<dim3(10, 10, 4 * 4),  blk, 0, stream>>>(buf1,  ow2, ob2, buf2, 64,  64,  4);
    conv3x3_kernel<false, false><<<dim3(10, 10, 4 * 14), blk, 0, stream>>>(buf2,  ow3, ob3, raw,  64,  216, 14);

    // Modulated deformable conv + assembly into output frames {0,1,3,4}.
    mdcn_kernel<<<dim3(10, 10, 4), blk, 0, stream>>>(feats, raw, dw, db, out);
}

// Round 2
// 585.796 us; speedup vs baseline: 5.3832x; 5.3832x over previous
//
#include <hip/hip_runtime.h>
#include <hip/hip_bf16.h>
#include <math.h>

#define HH 160
#define WW 160
#define HWsz (HH*WW)

typedef short bf16x8 __attribute__((ext_vector_type(8)));
typedef float f32x4  __attribute__((ext_vector_type(4)));

__device__ inline ushort f2bf(float f) {
    unsigned int u = __float_as_uint(f);
    unsigned int r = (u + 0x7FFFu + ((u >> 16) & 1u)) >> 16;
    return (ushort)r;
}

__device__ inline void unpk8(uint4 u, float* f) {
    f[0] = __uint_as_float(u.x << 16); f[1] = __uint_as_float(u.x & 0xFFFF0000u);
    f[2] = __uint_as_float(u.y << 16); f[3] = __uint_as_float(u.y & 0xFFFF0000u);
    f[4] = __uint_as_float(u.z << 16); f[5] = __uint_as_float(u.z & 0xFFFF0000u);
    f[6] = __uint_as_float(u.w << 16); f[7] = __uint_as_float(u.w & 0xFFFF0000u);
}

// ---------------------------------------------------------------------------
// Weight pre-pack into MFMA A-fragment order:
// wp[(((tap*CIC + cic)*MT_TOT + mt)*64 + lane)*8 + j] =
//    bf16( W[co = mt*16 + (lane&15)][ci = cic*32 + (lane>>4)*8 + j][tap] )
// ---------------------------------------------------------------------------
__global__ __launch_bounds__(256)
void pack_weights(const float* __restrict__ w, ushort* __restrict__ wp,
                  int Cout, int Cin, int MT_TOT, int CIC)
{
    const int idx = blockIdx.x * 256 + threadIdx.x;
    const int total = 9 * CIC * MT_TOT * 64;
    if (idx >= total) return;
    const int lane = idx & 63;
    int t = idx >> 6;
    const int mt  = t % MT_TOT; t /= MT_TOT;
    const int cic = t % CIC;    t /= CIC;
    const int tap = t;
    const int co  = mt * 16 + (lane & 15);
    const int ci0 = cic * 32 + (lane >> 4) * 8;
    ushort v[8];
#pragma unroll
    for (int j = 0; j < 8; ++j) {
        const int ci = ci0 + j;
        float f = 0.f;
        if (co < Cout && ci < Cin) f = w[((size_t)co * Cin + ci) * 9 + tap];
        v[j] = f2bf(f);
    }
    uint4 pk;
    pk.x = (unsigned)v[0] | ((unsigned)v[1] << 16);
    pk.y = (unsigned)v[2] | ((unsigned)v[3] << 16);
    pk.z = (unsigned)v[4] | ((unsigned)v[5] << 16);
    pk.w = (unsigned)v[6] | ((unsigned)v[7] << 16);
    *(uint4*)(wp + (size_t)idx * 8) = pk;
}

// dw (64,64,3,3) NCHW -> dwp[((g*8+c)*9+k)*64 + o]  (f32, o-contiguous)
__global__ __launch_bounds__(256)
void pack_dw(const float* __restrict__ dw, float* __restrict__ dwp)
{
    const int i = blockIdx.x * 256 + threadIdx.x;
    if (i >= 64 * 64 * 9) return;
    const int o  = i & 63;
    const int r  = i >> 6;
    const int k  = r % 9;
    const int gc = r / 9;               // g*8+c
    dwp[i] = dw[((size_t)o * 64 + gc) * 9 + k];
}

// ---------------------------------------------------------------------------
// MFMA implicit-GEMM 3x3 SAME conv. NHWC bf16 in, NHWC bf16/f32 out.
// Block 256 thr (4 waves). Tile: 64 co x (ROWS x 32) px. Wave: 64co x 64px
// (ROWS=8) or 64co x 32px (ROWS=4). K-loop: 9 taps x CIC ci-chunks of 32.
// s_in: [ROWS+2][34][C8 slots of 16B], slot = ci8 ^ (col&7) (bank swizzle).
// CONCAT: logical Cin=128 = 64ch of feats[2] ++ 64ch of feats[fidx].
// ---------------------------------------------------------------------------
template<int ROWS, int CIC, bool CONCAT, bool RELU, bool OUTBF>
__global__ __launch_bounds__(256)
void mfma_conv(const ushort* __restrict__ in, const ushort* __restrict__ wp,
               const float* __restrict__ bias, void* __restrict__ outv,
               int Cout, int MT_TOT, int COG)
{
    constexpr int C8  = CIC * 4;
    constexpr int HR  = ROWS + 2;
    constexpr int NT  = (ROWS / 4) * 2;
    constexpr int CIN = CIC * 32;
    __shared__ uint4 s_in4[HR * 34 * C8];
    __shared__ uint4 s_w4[CIC * 4 * 64];

    const int tid = threadIdx.x;
    const int lane = tid & 63, wid = tid >> 6;
    const int lane15 = lane & 15, lgrp = lane >> 4;
    const int bz = blockIdx.z;
    const int frame = bz / COG, cog = bz % COG;
    const int x0 = blockIdx.x * 32, y0 = blockIdx.y * ROWS;

    const ushort* src = nullptr; const ushort* srcRef = nullptr; const ushort* srcCur = nullptr;
    if (CONCAT) {
        const int fidx = (frame < 2) ? frame : frame + 1;
        srcRef = in + (size_t)2 * HWsz * 64;
        srcCur = in + (size_t)fidx * HWsz * 64;
    } else {
        src = in + (size_t)frame * HWsz * CIN;
    }

    // ---- stage input halo tile ----
    for (int i = tid; i < HR * 34 * C8; i += 256) {
        const int ci8 = i & (C8 - 1);
        const int rem = i / C8;
        const int col = rem % 34, row = rem / 34;
        const int gy = y0 + row - 1, gx = x0 + col - 1;
        uint4 v = {0u, 0u, 0u, 0u};
        if (gy >= 0 && gy < HH && gx >= 0 && gx < WW) {
            if (CONCAT) {
                const ushort* sp = (ci8 < 8) ? srcRef : srcCur;
                v = *(const uint4*)(sp + (size_t)(gy * WW + gx) * 64 + (ci8 & 7) * 8);
            } else {
                v = *(const uint4*)(src + (size_t)(gy * WW + gx) * CIN + ci8 * 8);
            }
        }
        s_in4[(row * 34 + col) * C8 + (ci8 ^ (col & 7))] = v;
    }

    f32x4 acc[4][NT];
#pragma unroll
    for (int m = 0; m < 4; ++m)
#pragma unroll
        for (int n = 0; n < NT; ++n) acc[m][n] = (f32x4){0.f, 0.f, 0.f, 0.f};

    const uint4* wp4 = (const uint4*)wp;
    const int wrow = wid * (ROWS / 4);

    for (int tap = 0; tap < 9; ++tap) {
        // stage this tap's A-fragments (linear copy, conflict-free)
        for (int i = tid; i < CIC * 4 * 64; i += 256) {
            const int ln = i & 63, mtl = (i >> 6) & 3, cc = i >> 8;
            s_w4[i] = wp4[((size_t)(tap * CIC + cc) * MT_TOT + cog * 4 + mtl) * 64 + ln];
        }
        __syncthreads();

        const int dy  = tap / 3 - 1;
        const int dxp = tap % 3;          // col_l offset (dx+1)
#pragma unroll
        for (int cic = 0; cic < CIC; ++cic) {
            bf16x8 a[4];
#pragma unroll
            for (int mt = 0; mt < 4; ++mt)
                a[mt] = *(const bf16x8*)&s_w4[(cic * 4 + mt) * 64 + lane];
#pragma unroll
            for (int nt = 0; nt < NT; ++nt) {
                const int row_l = wrow + (nt >> 1) + dy + 1;
                const int col_l = (nt & 1) * 16 + lane15 + dxp;
                const bf16x8 b = *(const bf16x8*)
                    &s_in4[(row_l * 34 + col_l) * C8 + ((cic * 4 + lgrp) ^ (col_l & 7))];
#pragma unroll
                for (int mt = 0; mt < 4; ++mt)
                    acc[mt][nt] = __builtin_amdgcn_mfma_f32_16x16x32_bf16(a[mt], b, acc[mt][nt], 0, 0, 0);
            }
        }
        __syncthreads();
    }

    // ---- epilogue: D row = co (lgrp*4+reg), col = px (lane15) ----
#pragma unroll
    for (int mt = 0; mt < 4; ++mt) {
        const int co = cog * 64 + mt * 16 + lgrp * 4;
        if (co < Cout) {
            const float4 bs = *(const float4*)&bias[co];
#pragma unroll
            for (int nt = 0; nt < NT; ++nt) {
                const int yy = y0 + wrow + (nt >> 1);
                const int xx = x0 + (nt & 1) * 16 + lane15;
                f32x4 v = acc[mt][nt];
                v[0] += bs.x; v[1] += bs.y; v[2] += bs.z; v[3] += bs.w;
                if (RELU) {
                    v[0] = fmaxf(v[0], 0.f); v[1] = fmaxf(v[1], 0.f);
                    v[2] = fmaxf(v[2], 0.f); v[3] = fmaxf(v[3], 0.f);
                }
                const size_t po = ((size_t)frame * HWsz + yy * WW + xx) * (size_t)Cout + co;
                if (OUTBF) {
                    uint2 pk;
                    pk.x = (unsigned)f2bf(v[0]) | ((unsigned)f2bf(v[1]) << 16);
                    pk.y = (unsigned)f2bf(v[2]) | ((unsigned)f2bf(v[3]) << 16);
                    *(uint2*)((ushort*)outv + po) = pk;
                } else {
                    *(f32x4*)((float*)outv + po) = v;
                }
            }
        }
    }
}

// ---------------------------------------------------------------------------
// conv1: Cin=4 NCHW f32 -> 64ch NHWC bf16, direct VALU (tiny layer).
// ---------------------------------------------------------------------------
__global__ __launch_bounds__(256)
void conv1_kernel(const float* __restrict__ x, const float* __restrict__ w,
                  const float* __restrict__ b, ushort* __restrict__ out)
{
    const int fr = blockIdx.z;
    const int t = threadIdx.x;
    const int tx = t & 15, ty = t >> 4;
    const int x0 = blockIdx.x * 16, y0 = blockIdx.y * 16;

    __shared__ float s_x[4][18][18];
    __shared__ float s_w[36][64];     // [ci*9+tap][o]
    __shared__ float s_b[64];

    for (int i = t; i < 4 * 18 * 18; i += 256) {
        const int ci = i / 324, rem = i % 324;
        const int yy = rem / 18, xx = rem % 18;
        const int gy = y0 + yy - 1, gx = x0 + xx - 1;
        float v = 0.f;
        if (gy >= 0 && gy < HH && gx >= 0 && gx < WW)
            v = x[((size_t)fr * 4 + ci) * HWsz + gy * WW + gx];
        s_x[ci][yy][xx] = v;
    }
    for (int i = t; i < 36 * 64; i += 256) {
        const int row = i / 64, o = i % 64;
        const int ci = row / 9, tap = row % 9;
        s_w[row][o] = w[((size_t)o * 4 + ci) * 9 + tap];
    }
    if (t < 64) s_b[t] = b[t];
    __syncthreads();

    float acc[64];
#pragma unroll
    for (int i = 0; i < 64; ++i) acc[i] = 0.f;

#pragma unroll
    for (int ci = 0; ci < 4; ++ci) {
#pragma unroll
        for (int tap = 0; tap < 9; ++tap) {
            const float v = s_x[ci][ty + tap / 3][tx + tap % 3];
            const float4* wr = (const float4*)&s_w[ci * 9 + tap][0];
#pragma unroll
            for (int o4 = 0; o4 < 16; ++o4) {
                const float4 wv = wr[o4];
                acc[o4 * 4 + 0] = fmaf(v, wv.x, acc[o4 * 4 + 0]);
                acc[o4 * 4 + 1] = fmaf(v, wv.y, acc[o4 * 4 + 1]);
                acc[o4 * 4 + 2] = fmaf(v, wv.z, acc[o4 * 4 + 2]);
                acc[o4 * 4 + 3] = fmaf(v, wv.w, acc[o4 * 4 + 3]);
            }
        }
    }

    ushort* ob = out + ((size_t)fr * HWsz + (y0 + ty) * WW + (x0 + tx)) * 64;
#pragma unroll
    for (int o8 = 0; o8 < 8; ++o8) {
        ushort v[8];
#pragma unroll
        for (int j = 0; j < 8; ++j)
            v[j] = f2bf(fmaxf(acc[o8 * 8 + j] + s_b[o8 * 8 + j], 0.f));
        uint4 pk;
        pk.x = (unsigned)v[0] | ((unsigned)v[1] << 16);
        pk.y = (unsigned)v[2] | ((unsigned)v[3] << 16);
        pk.z = (unsigned)v[4] | ((unsigned)v[5] << 16);
        pk.w = (unsigned)v[6] | ((unsigned)v[7] << 16);
        *(uint4*)(ob + o8 * 8) = pk;
    }
}

// feats[2] NHWC bf16 -> out frame 2 NCHW f32
__global__ __launch_bounds__(256)
void copy_ref_kernel(const ushort* __restrict__ fts, float* __restrict__ out)
{
    const int px = blockIdx.x * 256 + threadIdx.x;
    if (px >= HWsz) return;
    const uint4* p = (const uint4*)(fts + ((size_t)2 * HWsz + px) * 64);
    float* ob = out + (size_t)2 * 64 * HWsz + px;
#pragma unroll
    for (int o8 = 0; o8 < 8; ++o8) {
        float f[8];
        unpk8(p[o8], f);
#pragma unroll
        for (int j = 0; j < 8; ++j)
            ob[(size_t)(o8 * 8 + j) * HWsz] = f[j];
    }
}

// ---------------------------------------------------------------------------
// MDCN: NHWC bf16 feats, NHWC f32 raw, packed dwp; NCHW f32 out.
// Block 128 thr = 16x8 px tile. Per-thread 64 acc; per-g weight slice in LDS.
// ---------------------------------------------------------------------------
__global__ __launch_bounds__(128)
void mdcn_kernel(const ushort* __restrict__ fts, const float* __restrict__ raw,
                 const float* __restrict__ dwp, const float* __restrict__ db,
                 float* __restrict__ out)
{
    const int b    = blockIdx.z;
    const int fidx = (b < 2) ? b : b + 1;
    const int t  = threadIdx.x;
    const int tx = t & 15, ty = t >> 4;
    const int w  = blockIdx.x * 16 + tx;
    const int h  = blockIdx.y * 8 + ty;
    const int hw = h * WW + w;

    __shared__ float s_w[8 * 9 * 64];   // [c*9+k][o]

    float acc[64];
#pragma unroll
    for (int i = 0; i < 64; ++i) acc[i] = 0.f;

    const float*  rawp = raw + ((size_t)b * HWsz + hw) * 216;
    const ushort* xb   = fts + (size_t)fidx * HWsz * 64;

    for (int g = 0; g < 8; ++g) {
        __syncthreads();
        {
            const float4* sp = (const float4*)(dwp + (size_t)g * 4608);
            float4* dp = (float4*)s_w;
            for (int i = t; i < 1152; i += 128) dp[i] = sp[i];
        }
        __syncthreads();

        const ushort* pb = xb + g * 8;
        for (int k = 0; k < 9; ++k) {
            const int kyy = k / 3 - 1, kxx = k % 3 - 1;
            const float oy = rawp[g * 18 + 2 * k + 0];
            const float ox = rawp[g * 18 + 2 * k + 1];
            float mv = rawp[144 + g * 9 + k];
            mv = 1.f / (1.f + __expf(-mv));

            const float py = oy + (float)(h + kyy);
            const float px = ox + (float)(w + kxx);
            const float y0f = floorf(py), x0f = floorf(px);
            const float tyf = py - y0f, txf = px - x0f;
            const int y0 = (int)y0f, x0i = (int)x0f;
            const int y1 = y0 + 1, x1 = x0i + 1;
            const bool vy0 = (y0 >= 0) & (y0 < HH);
            const bool vy1 = (y1 >= 0) & (y1 < HH);
            const bool vx0 = (x0i >= 0) & (x0i < WW);
            const bool vx1 = (x1 >= 0) & (x1 < WW);
            const int yc0 = min(max(y0, 0), HH - 1), yc1 = min(max(y1, 0), HH - 1);
            const int xc0 = min(max(x0i, 0), WW - 1), xc1 = min(max(x1, 0), WW - 1);
            float w00 = (1.f - tyf) * (1.f - txf) * mv;
            float w01 = (1.f - tyf) * txf * mv;
            float w10 = tyf * (1.f - txf) * mv;
            float w11 = tyf * txf * mv;
            if (!(vy0 && vx0)) w00 = 0.f;
            if (!(vy0 && vx1)) w01 = 0.f;
            if (!(vy1 && vx0)) w10 = 0.f;
            if (!(vy1 && vx1)) w11 = 0.f;

            const uint4 u00 = *(const uint4*)(pb + (size_t)(yc0 * WW + xc0) * 64);
            const uint4 u01 = *(const uint4*)(pb + (size_t)(yc0 * WW + xc1) * 64);
            const uint4 u10 = *(const uint4*)(pb + (size_t)(yc1 * WW + xc0) * 64);
            const uint4 u11 = *(const uint4*)(pb + (size_t)(yc1 * WW + xc1) * 64);
            float f00[8], f01[8], f10[8], f11[8];
            unpk8(u00, f00); unpk8(u01, f01); unpk8(u10, f10); unpk8(u11, f11);

#pragma unroll
            for (int c = 0; c < 8; ++c) {
                const float v = w00 * f00[c] + w01 * f01[c] + w10 * f10[c] + w11 * f11[c];
                const float4* wl = (const float4*)&s_w[(c * 9 + k) * 64];
#pragma unroll
                for (int o4 = 0; o4 < 16; ++o4) {
                    const float4 wv = wl[o4];
                    acc[o4 * 4 + 0] = fmaf(v, wv.x, acc[o4 * 4 + 0]);
                    acc[o4 * 4 + 1] = fmaf(v, wv.y, acc[o4 * 4 + 1]);
                    acc[o4 * 4 + 2] = fmaf(v, wv.z, acc[o4 * 4 + 2]);
                    acc[o4 * 4 + 3] = fmaf(v, wv.w, acc[o4 * 4 + 3]);
                }
            }
        }
    }

    float* ob = out + (size_t)fidx * 64 * HWsz + hw;
#pragma unroll
    for (int o = 0; o < 64; ++o)
        ob[(size_t)o * HWsz] = acc[o] + db[o];
}

extern "C" void kernel_launch(void* const* d_in, const int* in_sizes, int n_in,
                              void* d_out, int out_size, void* d_ws, size_t ws_size,
                              hipStream_t stream)
{
    const float* x   = (const float*)d_in[0];
    const float* fw1 = (const float*)d_in[1];
    const float* fb1 = (const float*)d_in[2];
    const float* fw2 = (const float*)d_in[3];
    const float* fb2 = (const float*)d_in[4];
    const float* fw3 = (const float*)d_in[5];
    const float* fb3 = (const float*)d_in[6];
    const float* ow1 = (const float*)d_in[7];
    const float* ob1 = (const float*)d_in[8];
    const float* ow2 = (const float*)d_in[9];
    const float* ob2 = (const float*)d_in[10];
    const float* ow3 = (const float*)d_in[11];
    const float* ob3 = (const float*)d_in[12];
    const float* dw  = (const float*)d_in[13];
    const float* db  = (const float*)d_in[14];
    float* out = (float*)d_out;

    // ---- workspace layout (bytes all 16B aligned) ----
    ushort* buf1 = (ushort*)d_ws;                 // 5*HW*64 bf16
    ushort* buf2 = buf1 + (size_t)5 * HWsz * 64;
    ushort* fts  = buf2 + (size_t)5 * HWsz * 64;
    float*  raw  = (float*)(fts + (size_t)5 * HWsz * 64);   // 4*HW*216 f32
    ushort* w2p  = (ushort*)(raw + (size_t)4 * HWsz * 216);
    ushort* w3p  = w2p + 36864;
    ushort* o1p  = w3p + 36864;
    ushort* o2p  = o1p + 73728;
    ushort* o3p  = o2p + 36864;
    float*  dwp  = (float*)(o3p + 147456);

    const dim3 blk(256);

    // ---- weight packing ----
    pack_weights<<<dim3(18),  blk, 0, stream>>>(fw2, w2p, 64, 64, 4, 2);
    pack_weights<<<dim3(18),  blk, 0, stream>>>(fw3, w3p, 64, 64, 4, 2);
    pack_weights<<<dim3(36),  blk, 0, stream>>>(ow1, o1p, 64, 128, 4, 4);
    pack_weights<<<dim3(18),  blk, 0, stream>>>(ow2, o2p, 64, 64, 4, 2);
    pack_weights<<<dim3(72),  blk, 0, stream>>>(ow3, o3p, 216, 64, 16, 2);
    pack_dw<<<dim3(144), blk, 0, stream>>>(dw, dwp);

    // ---- feature extraction ----
    conv1_kernel<<<dim3(10, 10, 5), blk, 0, stream>>>(x, fw1, fb1, buf1);
    mfma_conv<8, 2, false, true, true><<<dim3(5, 20, 5), blk, 0, stream>>>(
        buf1, w2p, fb2, buf2, 64, 4, 1);
    mfma_conv<8, 2, false, true, true><<<dim3(5, 20, 5), blk, 0, stream>>>(
        buf2, w3p, fb3, fts, 64, 4, 1);

    copy_ref_kernel<<<dim3(100), blk, 0, stream>>>(fts, out);

    // ---- offset network ----
    mfma_conv<4, 4, true, true, true><<<dim3(5, 40, 4), blk, 0, stream>>>(
        fts, o1p, ob1, buf1, 64, 4, 1);
    mfma_conv<8, 2, false, true, true><<<dim3(5, 20, 4), blk, 0, stream>>>(
        buf1, o2p, ob2, buf2, 64, 4, 1);
    mfma_conv<8, 2, false, false, false><<<dim3(5, 20, 16), blk, 0, stream>>>(
        buf2, o3p, ob3, raw, 216, 16, 4);

    // ---- modulated deformable conv + assembly ----
    mdcn_kernel<<<dim3(10, 20, 4), dim3(128), 0, stream>>>(fts, raw, dwp, db, out);
}

// Round 3
// 428.314 us; speedup vs baseline: 7.3626x; 1.3677x over previous
//
#include <hip/hip_runtime.h>
#include <hip/hip_bf16.h>
#include <math.h>

#define HH 160
#define WW 160
#define HWsz (HH*WW)

typedef short bf16x8 __attribute__((ext_vector_type(8)));
typedef float f32x4  __attribute__((ext_vector_type(4)));

__device__ inline ushort f2bf(float f) {
    unsigned int u = __float_as_uint(f);
    unsigned int r = (u + 0x7FFFu + ((u >> 16) & 1u)) >> 16;
    return (ushort)r;
}

__device__ inline void unpk8(uint4 u, float* f) {
    f[0] = __uint_as_float(u.x << 16); f[1] = __uint_as_float(u.x & 0xFFFF0000u);
    f[2] = __uint_as_float(u.y << 16); f[3] = __uint_as_float(u.y & 0xFFFF0000u);
    f[4] = __uint_as_float(u.z << 16); f[5] = __uint_as_float(u.z & 0xFFFF0000u);
    f[6] = __uint_as_float(u.w << 16); f[7] = __uint_as_float(u.w & 0xFFFF0000u);
}

// ---------------------------------------------------------------------------
// Weight pre-pack into MFMA A-fragment order (unchanged from round 2).
// ---------------------------------------------------------------------------
__global__ __launch_bounds__(256)
void pack_weights(const float* __restrict__ w, ushort* __restrict__ wp,
                  int Cout, int Cin, int MT_TOT, int CIC)
{
    const int idx = blockIdx.x * 256 + threadIdx.x;
    const int total = 9 * CIC * MT_TOT * 64;
    if (idx >= total) return;
    const int lane = idx & 63;
    int t = idx >> 6;
    const int mt  = t % MT_TOT; t /= MT_TOT;
    const int cic = t % CIC;    t /= CIC;
    const int tap = t;
    const int co  = mt * 16 + (lane & 15);
    const int ci0 = cic * 32 + (lane >> 4) * 8;
    ushort v[8];
#pragma unroll
    for (int j = 0; j < 8; ++j) {
        const int ci = ci0 + j;
        float f = 0.f;
        if (co < Cout && ci < Cin) f = w[((size_t)co * Cin + ci) * 9 + tap];
        v[j] = f2bf(f);
    }
    uint4 pk;
    pk.x = (unsigned)v[0] | ((unsigned)v[1] << 16);
    pk.y = (unsigned)v[2] | ((unsigned)v[3] << 16);
    pk.z = (unsigned)v[4] | ((unsigned)v[5] << 16);
    pk.w = (unsigned)v[6] | ((unsigned)v[7] << 16);
    *(uint4*)(wp + (size_t)idx * 8) = pk;
}

// dw (64,64,3,3) NCHW -> dwp[((g*8+c)*9+k)*64 + o]  (f32, o-contiguous)
__global__ __launch_bounds__(256)
void pack_dw(const float* __restrict__ dw, float* __restrict__ dwp)
{
    const int i = blockIdx.x * 256 + threadIdx.x;
    if (i >= 64 * 64 * 9) return;
    const int o  = i & 63;
    const int r  = i >> 6;
    const int k  = r % 9;
    const int gc = r / 9;               // g*8+c
    dwp[i] = dw[((size_t)o * 64 + gc) * 9 + k];
}

// ---------------------------------------------------------------------------
// MFMA implicit-GEMM 3x3 SAME conv (unchanged from round 2).
// ---------------------------------------------------------------------------
template<int ROWS, int CIC, bool CONCAT, bool RELU, bool OUTBF>
__global__ __launch_bounds__(256)
void mfma_conv(const ushort* __restrict__ in, const ushort* __restrict__ wp,
               const float* __restrict__ bias, void* __restrict__ outv,
               int Cout, int MT_TOT, int COG)
{
    constexpr int C8  = CIC * 4;
    constexpr int HR  = ROWS + 2;
    constexpr int NT  = (ROWS / 4) * 2;
    constexpr int CIN = CIC * 32;
    __shared__ uint4 s_in4[HR * 34 * C8];
    __shared__ uint4 s_w4[CIC * 4 * 64];

    const int tid = threadIdx.x;
    const int lane = tid & 63, wid = tid >> 6;
    const int lane15 = lane & 15, lgrp = lane >> 4;
    const int bz = blockIdx.z;
    const int frame = bz / COG, cog = bz % COG;
    const int x0 = blockIdx.x * 32, y0 = blockIdx.y * ROWS;

    const ushort* src = nullptr; const ushort* srcRef = nullptr; const ushort* srcCur = nullptr;
    if (CONCAT) {
        const int fidx = (frame < 2) ? frame : frame + 1;
        srcRef = in + (size_t)2 * HWsz * 64;
        srcCur = in + (size_t)fidx * HWsz * 64;
    } else {
        src = in + (size_t)frame * HWsz * CIN;
    }

    // ---- stage input halo tile ----
    for (int i = tid; i < HR * 34 * C8; i += 256) {
        const int ci8 = i & (C8 - 1);
        const int rem = i / C8;
        const int col = rem % 34, row = rem / 34;
        const int gy = y0 + row - 1, gx = x0 + col - 1;
        uint4 v = {0u, 0u, 0u, 0u};
        if (gy >= 0 && gy < HH && gx >= 0 && gx < WW) {
            if (CONCAT) {
                const ushort* sp = (ci8 < 8) ? srcRef : srcCur;
                v = *(const uint4*)(sp + (size_t)(gy * WW + gx) * 64 + (ci8 & 7) * 8);
            } else {
                v = *(const uint4*)(src + (size_t)(gy * WW + gx) * CIN + ci8 * 8);
            }
        }
        s_in4[(row * 34 + col) * C8 + (ci8 ^ (col & 7))] = v;
    }

    f32x4 acc[4][NT];
#pragma unroll
    for (int m = 0; m < 4; ++m)
#pragma unroll
        for (int n = 0; n < NT; ++n) acc[m][n] = (f32x4){0.f, 0.f, 0.f, 0.f};

    const uint4* wp4 = (const uint4*)wp;
    const int wrow = wid * (ROWS / 4);

    for (int tap = 0; tap < 9; ++tap) {
        for (int i = tid; i < CIC * 4 * 64; i += 256) {
            const int ln = i & 63, mtl = (i >> 6) & 3, cc = i >> 8;
            s_w4[i] = wp4[((size_t)(tap * CIC + cc) * MT_TOT + cog * 4 + mtl) * 64 + ln];
        }
        __syncthreads();

        const int dy  = tap / 3 - 1;
        const int dxp = tap % 3;
#pragma unroll
        for (int cic = 0; cic < CIC; ++cic) {
            bf16x8 a[4];
#pragma unroll
            for (int mt = 0; mt < 4; ++mt)
                a[mt] = *(const bf16x8*)&s_w4[(cic * 4 + mt) * 64 + lane];
#pragma unroll
            for (int nt = 0; nt < NT; ++nt) {
                const int row_l = wrow + (nt >> 1) + dy + 1;
                const int col_l = (nt & 1) * 16 + lane15 + dxp;
                const bf16x8 b = *(const bf16x8*)
                    &s_in4[(row_l * 34 + col_l) * C8 + ((cic * 4 + lgrp) ^ (col_l & 7))];
#pragma unroll
                for (int mt = 0; mt < 4; ++mt)
                    acc[mt][nt] = __builtin_amdgcn_mfma_f32_16x16x32_bf16(a[mt], b, acc[mt][nt], 0, 0, 0);
            }
        }
        __syncthreads();
    }

#pragma unroll
    for (int mt = 0; mt < 4; ++mt) {
        const int co = cog * 64 + mt * 16 + lgrp * 4;
        if (co < Cout) {
            const float4 bs = *(const float4*)&bias[co];
#pragma unroll
            for (int nt = 0; nt < NT; ++nt) {
                const int yy = y0 + wrow + (nt >> 1);
                const int xx = x0 + (nt & 1) * 16 + lane15;
                f32x4 v = acc[mt][nt];
                v[0] += bs.x; v[1] += bs.y; v[2] += bs.z; v[3] += bs.w;
                if (RELU) {
                    v[0] = fmaxf(v[0], 0.f); v[1] = fmaxf(v[1], 0.f);
                    v[2] = fmaxf(v[2], 0.f); v[3] = fmaxf(v[3], 0.f);
                }
                const size_t po = ((size_t)frame * HWsz + yy * WW + xx) * (size_t)Cout + co;
                if (OUTBF) {
                    uint2 pk;
                    pk.x = (unsigned)f2bf(v[0]) | ((unsigned)f2bf(v[1]) << 16);
                    pk.y = (unsigned)f2bf(v[2]) | ((unsigned)f2bf(v[3]) << 16);
                    *(uint2*)((ushort*)outv + po) = pk;
                } else {
                    *(f32x4*)((float*)outv + po) = v;
                }
            }
        }
    }
}

// ---------------------------------------------------------------------------
// conv1 (unchanged).
// ---------------------------------------------------------------------------
__global__ __launch_bounds__(256)
void conv1_kernel(const float* __restrict__ x, const float* __restrict__ w,
                  const float* __restrict__ b, ushort* __restrict__ out)
{
    const int fr = blockIdx.z;
    const int t = threadIdx.x;
    const int tx = t & 15, ty = t >> 4;
    const int x0 = blockIdx.x * 16, y0 = blockIdx.y * 16;

    __shared__ float s_x[4][18][18];
    __shared__ float s_w[36][64];
    __shared__ float s_b[64];

    for (int i = t; i < 4 * 18 * 18; i += 256) {
        const int ci = i / 324, rem = i % 324;
        const int yy = rem / 18, xx = rem % 18;
        const int gy = y0 + yy - 1, gx = x0 + xx - 1;
        float v = 0.f;
        if (gy >= 0 && gy < HH && gx >= 0 && gx < WW)
            v = x[((size_t)fr * 4 + ci) * HWsz + gy * WW + gx];
        s_x[ci][yy][xx] = v;
    }
    for (int i = t; i < 36 * 64; i += 256) {
        const int row = i / 64, o = i % 64;
        const int ci = row / 9, tap = row % 9;
        s_w[row][o] = w[((size_t)o * 4 + ci) * 9 + tap];
    }
    if (t < 64) s_b[t] = b[t];
    __syncthreads();

    float acc[64];
#pragma unroll
    for (int i = 0; i < 64; ++i) acc[i] = 0.f;

#pragma unroll
    for (int ci = 0; ci < 4; ++ci) {
#pragma unroll
        for (int tap = 0; tap < 9; ++tap) {
            const float v = s_x[ci][ty + tap / 3][tx + tap % 3];
            const float4* wr = (const float4*)&s_w[ci * 9 + tap][0];
#pragma unroll
            for (int o4 = 0; o4 < 16; ++o4) {
                const float4 wv = wr[o4];
                acc[o4 * 4 + 0] = fmaf(v, wv.x, acc[o4 * 4 + 0]);
                acc[o4 * 4 + 1] = fmaf(v, wv.y, acc[o4 * 4 + 1]);
                acc[o4 * 4 + 2] = fmaf(v, wv.z, acc[o4 * 4 + 2]);
                acc[o4 * 4 + 3] = fmaf(v, wv.w, acc[o4 * 4 + 3]);
            }
        }
    }

    ushort* ob = out + ((size_t)fr * HWsz + (y0 + ty) * WW + (x0 + tx)) * 64;
#pragma unroll
    for (int o8 = 0; o8 < 8; ++o8) {
        ushort v[8];
#pragma unroll
        for (int j = 0; j < 8; ++j)
            v[j] = f2bf(fmaxf(acc[o8 * 8 + j] + s_b[o8 * 8 + j], 0.f));
        uint4 pk;
        pk.x = (unsigned)v[0] | ((unsigned)v[1] << 16);
        pk.y = (unsigned)v[2] | ((unsigned)v[3] << 16);
        pk.z = (unsigned)v[4] | ((unsigned)v[5] << 16);
        pk.w = (unsigned)v[6] | ((unsigned)v[7] << 16);
        *(uint4*)(ob + o8 * 8) = pk;
    }
}

// feats[2] NHWC bf16 -> out frame 2 NCHW f32
__global__ __launch_bounds__(256)
void copy_ref_kernel(const ushort* __restrict__ fts, float* __restrict__ out)
{
    const int px = blockIdx.x * 256 + threadIdx.x;
    if (px >= HWsz) return;
    const uint4* p = (const uint4*)(fts + ((size_t)2 * HWsz + px) * 64);
    float* ob = out + (size_t)2 * 64 * HWsz + px;
#pragma unroll
    for (int o8 = 0; o8 < 8; ++o8) {
        float f[8];
        unpk8(p[o8], f);
#pragma unroll
        for (int j = 0; j < 8; ++j)
            ob[(size_t)(o8 * 8 + j) * HWsz] = f[j];
    }
}

// fts NHWC64 -> group-major ftsg[(b,g,hw,8ch)] for the 4 non-center frames.
__global__ __launch_bounds__(256)
void repack_feats(const ushort* __restrict__ fts, ushort* __restrict__ ftsg)
{
    const int px = blockIdx.x * 256 + threadIdx.x;
    const int b  = blockIdx.y;
    if (px >= HWsz) return;
    const int fidx = (b < 2) ? b : b + 1;
    const uint4* src = (const uint4*)(fts + ((size_t)fidx * HWsz + px) * 64);
    uint4 v[8];
#pragma unroll
    for (int g = 0; g < 8; ++g) v[g] = src[g];
#pragma unroll
    for (int g = 0; g < 8; ++g)
        *(uint4*)(ftsg + ((size_t)(b * 8 + g) * HWsz + px) * 8) = v[g];
}

// ---------------------------------------------------------------------------
// MDCN v2: group-major bf16 feats (16B/px records -> coalesced-ish gathers),
// weights read directly from global with wave-uniform indices (s_load
// broadcast, no LDS). Block 256 thr = 16x16 px tile, 1 px/thread, 64 acc.
// ---------------------------------------------------------------------------
__global__ __launch_bounds__(256)
void mdcn_kernel(const ushort* __restrict__ ftsg, const float* __restrict__ raw,
                 const float* __restrict__ dwp, const float* __restrict__ db,
                 float* __restrict__ out)
{
    const int b    = blockIdx.z;
    const int fidx = (b < 2) ? b : b + 1;
    const int t  = threadIdx.x;
    const int tx = t & 15, ty = t >> 4;
    const int w  = blockIdx.x * 16 + tx;
    const int h  = blockIdx.y * 16 + ty;
    const int hw = h * WW + w;

    float acc[64];
#pragma unroll
    for (int i = 0; i < 64; ++i) acc[i] = 0.f;

    const float* rawp = raw + ((size_t)b * HWsz + hw) * 216;

    for (int g = 0; g < 8; ++g) {
        const float* __restrict__ wg = dwp + (size_t)g * 4608;   // [c*9+k][64]
        const ushort* __restrict__ pb = ftsg + (size_t)(b * 8 + g) * HWsz * 8;

        float offv[18], mskv[9];
#pragma unroll
        for (int i = 0; i < 18; ++i) offv[i] = rawp[g * 18 + i];
#pragma unroll
        for (int i = 0; i < 9; ++i) {
            const float m = rawp[144 + g * 9 + i];
            mskv[i] = 1.f / (1.f + __expf(-m));
        }

        for (int k = 0; k < 9; ++k) {
            const int kyy = k / 3 - 1, kxx = k % 3 - 1;
            const float py = offv[2 * k + 0] + (float)(h + kyy);
            const float px = offv[2 * k + 1] + (float)(w + kxx);
            const float mv = mskv[k];

            const float y0f = floorf(py), x0f = floorf(px);
            const float tyf = py - y0f, txf = px - x0f;
            const int y0 = (int)y0f, x0i = (int)x0f;
            const int y1 = y0 + 1, x1 = x0i + 1;
            const bool vy0 = (y0 >= 0) & (y0 < HH);
            const bool vy1 = (y1 >= 0) & (y1 < HH);
            const bool vx0 = (x0i >= 0) & (x0i < WW);
            const bool vx1 = (x1 >= 0) & (x1 < WW);
            const int yc0 = min(max(y0, 0), HH - 1), yc1 = min(max(y1, 0), HH - 1);
            const int xc0 = min(max(x0i, 0), WW - 1), xc1 = min(max(x1, 0), WW - 1);
            float w00 = (1.f - tyf) * (1.f - txf) * mv;
            float w01 = (1.f - tyf) * txf * mv;
            float w10 = tyf * (1.f - txf) * mv;
            float w11 = tyf * txf * mv;
            if (!(vy0 && vx0)) w00 = 0.f;
            if (!(vy0 && vx1)) w01 = 0.f;
            if (!(vy1 && vx0)) w10 = 0.f;
            if (!(vy1 && vx1)) w11 = 0.f;

            const uint4 u00 = *(const uint4*)(pb + (size_t)(yc0 * WW + xc0) * 8);
            const uint4 u01 = *(const uint4*)(pb + (size_t)(yc0 * WW + xc1) * 8);
            const uint4 u10 = *(const uint4*)(pb + (size_t)(yc1 * WW + xc0) * 8);
            const uint4 u11 = *(const uint4*)(pb + (size_t)(yc1 * WW + xc1) * 8);
            float f00[8], f01[8], f10[8], f11[8];
            unpk8(u00, f00); unpk8(u01, f01); unpk8(u10, f10); unpk8(u11, f11);

#pragma unroll
            for (int c = 0; c < 8; ++c) {
                const float v = w00 * f00[c] + w01 * f01[c] + w10 * f10[c] + w11 * f11[c];
                // wave-uniform index -> s_load broadcast, no LDS
                const float* __restrict__ wl = wg + (c * 9 + k) * 64;
#pragma unroll
                for (int o4 = 0; o4 < 16; ++o4) {
                    const float4 wv = *(const float4*)(wl + o4 * 4);
                    acc[o4 * 4 + 0] = fmaf(v, wv.x, acc[o4 * 4 + 0]);
                    acc[o4 * 4 + 1] = fmaf(v, wv.y, acc[o4 * 4 + 1]);
                    acc[o4 * 4 + 2] = fmaf(v, wv.z, acc[o4 * 4 + 2]);
                    acc[o4 * 4 + 3] = fmaf(v, wv.w, acc[o4 * 4 + 3]);
                }
            }
        }
    }

    float* ob = out + (size_t)fidx * 64 * HWsz + hw;
#pragma unroll
    for (int o = 0; o < 64; ++o)
        ob[(size_t)o * HWsz] = acc[o] + db[o];
}

extern "C" void kernel_launch(void* const* d_in, const int* in_sizes, int n_in,
                              void* d_out, int out_size, void* d_ws, size_t ws_size,
                              hipStream_t stream)
{
    const float* x   = (const float*)d_in[0];
    const float* fw1 = (const float*)d_in[1];
    const float* fb1 = (const float*)d_in[2];
    const float* fw2 = (const float*)d_in[3];
    const float* fb2 = (const float*)d_in[4];
    const float* fw3 = (const float*)d_in[5];
    const float* fb3 = (const float*)d_in[6];
    const float* ow1 = (const float*)d_in[7];
    const float* ob1 = (const float*)d_in[8];
    const float* ow2 = (const float*)d_in[9];
    const float* ob2 = (const float*)d_in[10];
    const float* ow3 = (const float*)d_in[11];
    const float* ob3 = (const float*)d_in[12];
    const float* dw  = (const float*)d_in[13];
    const float* db  = (const float*)d_in[14];
    float* out = (float*)d_out;

    // ---- workspace layout ----
    ushort* buf1 = (ushort*)d_ws;                     // 5*HW*64 bf16
    ushort* buf2 = buf1 + (size_t)5 * HWsz * 64;
    ushort* fts  = buf2 + (size_t)5 * HWsz * 64;
    ushort* ftsg = fts + (size_t)5 * HWsz * 64;       // 4*8*HW*8 bf16
    float*  raw  = (float*)(ftsg + (size_t)4 * 8 * HWsz * 8);  // 4*HW*216 f32
    ushort* w2p  = (ushort*)(raw + (size_t)4 * HWsz * 216);
    ushort* w3p  = w2p + 36864;
    ushort* o1p  = w3p + 36864;
    ushort* o2p  = o1p + 73728;
    ushort* o3p  = o2p + 36864;
    float*  dwp  = (float*)(o3p + 147456);

    const dim3 blk(256);

    // ---- weight packing ----
    pack_weights<<<dim3(18),  blk, 0, stream>>>(fw2, w2p, 64, 64, 4, 2);
    pack_weights<<<dim3(18),  blk, 0, stream>>>(fw3, w3p, 64, 64, 4, 2);
    pack_weights<<<dim3(36),  blk, 0, stream>>>(ow1, o1p, 64, 128, 4, 4);
    pack_weights<<<dim3(18),  blk, 0, stream>>>(ow2, o2p, 64, 64, 4, 2);
    pack_weights<<<dim3(72),  blk, 0, stream>>>(ow3, o3p, 216, 64, 16, 2);
    pack_dw<<<dim3(144), blk, 0, stream>>>(dw, dwp);

    // ---- feature extraction ----
    conv1_kernel<<<dim3(10, 10, 5), blk, 0, stream>>>(x, fw1, fb1, buf1);
    mfma_conv<8, 2, false, true, true><<<dim3(5, 20, 5), blk, 0, stream>>>(
        buf1, w2p, fb2, buf2, 64, 4, 1);
    mfma_conv<8, 2, false, true, true><<<dim3(5, 20, 5), blk, 0, stream>>>(
        buf2, w3p, fb3, fts, 64, 4, 1);

    copy_ref_kernel<<<dim3(100), blk, 0, stream>>>(fts, out);
    repack_feats<<<dim3(100, 4), blk, 0, stream>>>(fts, ftsg);

    // ---- offset network ----
    mfma_conv<4, 4, true, true, true><<<dim3(5, 40, 4), blk, 0, stream>>>(
        fts, o1p, ob1, buf1, 64, 4, 1);
    mfma_conv<8, 2, false, true, true><<<dim3(5, 20, 4), blk, 0, stream>>>(
        buf1, o2p, ob2, buf2, 64, 4, 1);
    mfma_conv<8, 2, false, false, false><<<dim3(5, 20, 16), blk, 0, stream>>>(
        buf2, o3p, ob3, raw, 216, 16, 4);

    // ---- modulated deformable conv + assembly ----
    mdcn_kernel<<<dim3(10, 10, 4), blk, 0, stream>>>(ftsg, raw, dwp, db, out);
}

// Round 4
// 260.515 us; speedup vs baseline: 12.1048x; 1.6441x over previous
//
#include <hip/hip_runtime.h>
#include <hip/hip_bf16.h>
#include <math.h>

#define HH 160
#define WW 160
#define HWsz (HH*WW)

typedef short bf16x8 __attribute__((ext_vector_type(8)));
typedef float f32x4  __attribute__((ext_vector_type(4)));

__device__ inline ushort f2bf(float f) {
    unsigned int u = __float_as_uint(f);
    unsigned int r = (u + 0x7FFFu + ((u >> 16) & 1u)) >> 16;
    return (ushort)r;
}

__device__ inline void unpk8(uint4 u, float* f) {
    f[0] = __uint_as_float(u.x << 16); f[1] = __uint_as_float(u.x & 0xFFFF0000u);
    f[2] = __uint_as_float(u.y << 16); f[3] = __uint_as_float(u.y & 0xFFFF0000u);
    f[4] = __uint_as_float(u.z << 16); f[5] = __uint_as_float(u.z & 0xFFFF0000u);
    f[6] = __uint_as_float(u.w << 16); f[7] = __uint_as_float(u.w & 0xFFFF0000u);
}

// ---------------------------------------------------------------------------
// Conv weight pre-pack into MFMA A-fragment order (unchanged).
// ---------------------------------------------------------------------------
__global__ __launch_bounds__(256)
void pack_weights(const float* __restrict__ w, ushort* __restrict__ wp,
                  int Cout, int Cin, int MT_TOT, int CIC)
{
    const int idx = blockIdx.x * 256 + threadIdx.x;
    const int total = 9 * CIC * MT_TOT * 64;
    if (idx >= total) return;
    const int lane = idx & 63;
    int t = idx >> 6;
    const int mt  = t % MT_TOT; t /= MT_TOT;
    const int cic = t % CIC;    t /= CIC;
    const int tap = t;
    const int co  = mt * 16 + (lane & 15);
    const int ci0 = cic * 32 + (lane >> 4) * 8;
    ushort v[8];
#pragma unroll
    for (int j = 0; j < 8; ++j) {
        const int ci = ci0 + j;
        float f = 0.f;
        if (co < Cout && ci < Cin) f = w[((size_t)co * Cin + ci) * 9 + tap];
        v[j] = f2bf(f);
    }
    uint4 pk;
    pk.x = (unsigned)v[0] | ((unsigned)v[1] << 16);
    pk.y = (unsigned)v[2] | ((unsigned)v[3] << 16);
    pk.z = (unsigned)v[4] | ((unsigned)v[5] << 16);
    pk.w = (unsigned)v[6] | ((unsigned)v[7] << 16);
    *(uint4*)(wp + (size_t)idx * 8) = pk;
}

// ---------------------------------------------------------------------------
// dw (64,64,3,3) -> MFMA A-fragment order for mdcn GEMM.
// K = (g,k,c): K = gk*8 + c, gk = g*9+k. wmp[((chunk*4+mt)*64+lane)*8+j]:
//   o = mt*16 + (lane&15), gk = chunk*4 + (lane>>4), c = j.
// ---------------------------------------------------------------------------
__global__ __launch_bounds__(256)
void pack_dw_mfma(const float* __restrict__ dw, ushort* __restrict__ wmp)
{
    const int idx = blockIdx.x * 256 + threadIdx.x;
    if (idx >= 18 * 4 * 64) return;
    const int lane = idx & 63;
    const int mt   = (idx >> 6) & 3;
    const int chunk = idx >> 8;
    const int o  = mt * 16 + (lane & 15);
    const int gk = chunk * 4 + (lane >> 4);
    const int g  = gk / 9, k = gk % 9;
    ushort v[8];
#pragma unroll
    for (int j = 0; j < 8; ++j)
        v[j] = f2bf(dw[((size_t)o * 64 + g * 8 + j) * 9 + k]);
    uint4 pk;
    pk.x = (unsigned)v[0] | ((unsigned)v[1] << 16);
    pk.y = (unsigned)v[2] | ((unsigned)v[3] << 16);
    pk.z = (unsigned)v[4] | ((unsigned)v[5] << 16);
    pk.w = (unsigned)v[6] | ((unsigned)v[7] << 16);
    *(uint4*)(wmp + (size_t)idx * 8) = pk;
}

// ---------------------------------------------------------------------------
// MFMA implicit-GEMM 3x3 SAME conv. OMODE: 0 = bf16 NHWC, 2 = f32 CHW.
// ---------------------------------------------------------------------------
template<int ROWS, int CIC, bool CONCAT, bool RELU, int OMODE>
__global__ __launch_bounds__(256)
void mfma_conv(const ushort* __restrict__ in, const ushort* __restrict__ wp,
               const float* __restrict__ bias, void* __restrict__ outv,
               int Cout, int MT_TOT, int COG)
{
    constexpr int C8  = CIC * 4;
    constexpr int HR  = ROWS + 2;
    constexpr int NT  = (ROWS / 4) * 2;
    constexpr int CIN = CIC * 32;
    __shared__ uint4 s_in4[HR * 34 * C8];
    __shared__ uint4 s_w4[CIC * 4 * 64];

    const int tid = threadIdx.x;
    const int lane = tid & 63, wid = tid >> 6;
    const int lane15 = lane & 15, lgrp = lane >> 4;
    const int bz = blockIdx.z;
    const int frame = bz / COG, cog = bz % COG;
    const int x0 = blockIdx.x * 32, y0 = blockIdx.y * ROWS;

    const ushort* src = nullptr; const ushort* srcRef = nullptr; const ushort* srcCur = nullptr;
    if (CONCAT) {
        const int fidx = (frame < 2) ? frame : frame + 1;
        srcRef = in + (size_t)2 * HWsz * 64;
        srcCur = in + (size_t)fidx * HWsz * 64;
    } else {
        src = in + (size_t)frame * HWsz * CIN;
    }

    for (int i = tid; i < HR * 34 * C8; i += 256) {
        const int ci8 = i & (C8 - 1);
        const int rem = i / C8;
        const int col = rem % 34, row = rem / 34;
        const int gy = y0 + row - 1, gx = x0 + col - 1;
        uint4 v = {0u, 0u, 0u, 0u};
        if (gy >= 0 && gy < HH && gx >= 0 && gx < WW) {
            if (CONCAT) {
                const ushort* sp = (ci8 < 8) ? srcRef : srcCur;
                v = *(const uint4*)(sp + (size_t)(gy * WW + gx) * 64 + (ci8 & 7) * 8);
            } else {
                v = *(const uint4*)(src + (size_t)(gy * WW + gx) * CIN + ci8 * 8);
            }
        }
        s_in4[(row * 34 + col) * C8 + (ci8 ^ (col & 7))] = v;
    }

    f32x4 acc[4][NT];
#pragma unroll
    for (int m = 0; m < 4; ++m)
#pragma unroll
        for (int n = 0; n < NT; ++n) acc[m][n] = (f32x4){0.f, 0.f, 0.f, 0.f};

    const uint4* wp4 = (const uint4*)wp;
    const int wrow = wid * (ROWS / 4);

    for (int tap = 0; tap < 9; ++tap) {
        for (int i = tid; i < CIC * 4 * 64; i += 256) {
            const int ln = i & 63, mtl = (i >> 6) & 3, cc = i >> 8;
            s_w4[i] = wp4[((size_t)(tap * CIC + cc) * MT_TOT + cog * 4 + mtl) * 64 + ln];
        }
        __syncthreads();

        const int dy  = tap / 3 - 1;
        const int dxp = tap % 3;
#pragma unroll
        for (int cic = 0; cic < CIC; ++cic) {
            bf16x8 a[4];
#pragma unroll
            for (int mt = 0; mt < 4; ++mt)
                a[mt] = *(const bf16x8*)&s_w4[(cic * 4 + mt) * 64 + lane];
#pragma unroll
            for (int nt = 0; nt < NT; ++nt) {
                const int row_l = wrow + (nt >> 1) + dy + 1;
                const int col_l = (nt & 1) * 16 + lane15 + dxp;
                const bf16x8 b = *(const bf16x8*)
                    &s_in4[(row_l * 34 + col_l) * C8 + ((cic * 4 + lgrp) ^ (col_l & 7))];
#pragma unroll
                for (int mt = 0; mt < 4; ++mt)
                    acc[mt][nt] = __builtin_amdgcn_mfma_f32_16x16x32_bf16(a[mt], b, acc[mt][nt], 0, 0, 0);
            }
        }
        __syncthreads();
    }

#pragma unroll
    for (int mt = 0; mt < 4; ++mt) {
        const int co = cog * 64 + mt * 16 + lgrp * 4;
        if (co < Cout) {
            const float4 bs = *(const float4*)&bias[co];
#pragma unroll
            for (int nt = 0; nt < NT; ++nt) {
                const int yy = y0 + wrow + (nt >> 1);
                const int xx = x0 + (nt & 1) * 16 + lane15;
                f32x4 v = acc[mt][nt];
                v[0] += bs.x; v[1] += bs.y; v[2] += bs.z; v[3] += bs.w;
                if (RELU) {
                    v[0] = fmaxf(v[0], 0.f); v[1] = fmaxf(v[1], 0.f);
                    v[2] = fmaxf(v[2], 0.f); v[3] = fmaxf(v[3], 0.f);
                }
                if (OMODE == 0) {
                    const size_t po = ((size_t)frame * HWsz + yy * WW + xx) * (size_t)Cout + co;
                    uint2 pk;
                    pk.x = (unsigned)f2bf(v[0]) | ((unsigned)f2bf(v[1]) << 16);
                    pk.y = (unsigned)f2bf(v[2]) | ((unsigned)f2bf(v[3]) << 16);
                    *(uint2*)((ushort*)outv + po) = pk;
                } else {
                    // f32 CHW: out[frame][co][hw]
                    float* of = (float*)outv;
                    const size_t base = ((size_t)frame * Cout + co) * HWsz + yy * WW + xx;
#pragma unroll
                    for (int j = 0; j < 4; ++j)
                        of[base + (size_t)j * HWsz] = v[j];
                }
            }
        }
    }
}

// ---------------------------------------------------------------------------
// conv1 (unchanged).
// ---------------------------------------------------------------------------
__global__ __launch_bounds__(256)
void conv1_kernel(const float* __restrict__ x, const float* __restrict__ w,
                  const float* __restrict__ b, ushort* __restrict__ out)
{
    const int fr = blockIdx.z;
    const int t = threadIdx.x;
    const int tx = t & 15, ty = t >> 4;
    const int x0 = blockIdx.x * 16, y0 = blockIdx.y * 16;

    __shared__ float s_x[4][18][18];
    __shared__ float s_w[36][64];
    __shared__ float s_b[64];

    for (int i = t; i < 4 * 18 * 18; i += 256) {
        const int ci = i / 324, rem = i % 324;
        const int yy = rem / 18, xx = rem % 18;
        const int gy = y0 + yy - 1, gx = x0 + xx - 1;
        float v = 0.f;
        if (gy >= 0 && gy < HH && gx >= 0 && gx < WW)
            v = x[((size_t)fr * 4 + ci) * HWsz + gy * WW + gx];
        s_x[ci][yy][xx] = v;
    }
    for (int i = t; i < 36 * 64; i += 256) {
        const int row = i / 64, o = i % 64;
        const int ci = row / 9, tap = row % 9;
        s_w[row][o] = w[((size_t)o * 4 + ci) * 9 + tap];
    }
    if (t < 64) s_b[t] = b[t];
    __syncthreads();

    float acc[64];
#pragma unroll
    for (int i = 0; i < 64; ++i) acc[i] = 0.f;

#pragma unroll
    for (int ci = 0; ci < 4; ++ci) {
#pragma unroll
        for (int tap = 0; tap < 9; ++tap) {
            const float v = s_x[ci][ty + tap / 3][tx + tap % 3];
            const float4* wr = (const float4*)&s_w[ci * 9 + tap][0];
#pragma unroll
            for (int o4 = 0; o4 < 16; ++o4) {
                const float4 wv = wr[o4];
                acc[o4 * 4 + 0] = fmaf(v, wv.x, acc[o4 * 4 + 0]);
                acc[o4 * 4 + 1] = fmaf(v, wv.y, acc[o4 * 4 + 1]);
                acc[o4 * 4 + 2] = fmaf(v, wv.z, acc[o4 * 4 + 2]);
                acc[o4 * 4 + 3] = fmaf(v, wv.w, acc[o4 * 4 + 3]);
            }
        }
    }

    ushort* ob = out + ((size_t)fr * HWsz + (y0 + ty) * WW + (x0 + tx)) * 64;
#pragma unroll
    for (int o8 = 0; o8 < 8; ++o8) {
        ushort v[8];
#pragma unroll
        for (int j = 0; j < 8; ++j)
            v[j] = f2bf(fmaxf(acc[o8 * 8 + j] + s_b[o8 * 8 + j], 0.f));
        uint4 pk;
        pk.x = (unsigned)v[0] | ((unsigned)v[1] << 16);
        pk.y = (unsigned)v[2] | ((unsigned)v[3] << 16);
        pk.z = (unsigned)v[4] | ((unsigned)v[5] << 16);
        pk.w = (unsigned)v[6] | ((unsigned)v[7] << 16);
        *(uint4*)(ob + o8 * 8) = pk;
    }
}

// feats[2] NHWC bf16 -> out frame 2 NCHW f32
__global__ __launch_bounds__(256)
void copy_ref_kernel(const ushort* __restrict__ fts, float* __restrict__ out)
{
    const int px = blockIdx.x * 256 + threadIdx.x;
    if (px >= HWsz) return;
    const uint4* p = (const uint4*)(fts + ((size_t)2 * HWsz + px) * 64);
    float* ob = out + (size_t)2 * 64 * HWsz + px;
#pragma unroll
    for (int o8 = 0; o8 < 8; ++o8) {
        float f[8];
        unpk8(p[o8], f);
#pragma unroll
        for (int j = 0; j < 8; ++j)
            ob[(size_t)(o8 * 8 + j) * HWsz] = f[j];
    }
}

// fts NHWC64 -> group-major ftsg[(b,g,hw,8ch)] for the 4 non-center frames.
__global__ __launch_bounds__(256)
void repack_feats(const ushort* __restrict__ fts, ushort* __restrict__ ftsg)
{
    const int px = blockIdx.x * 256 + threadIdx.x;
    const int b  = blockIdx.y;
    if (px >= HWsz) return;
    const int fidx = (b < 2) ? b : b + 1;
    const uint4* src = (const uint4*)(fts + ((size_t)fidx * HWsz + px) * 64);
    uint4 v[8];
#pragma unroll
    for (int g = 0; g < 8; ++g) v[g] = src[g];
#pragma unroll
    for (int g = 0; g < 8; ++g)
        *(uint4*)(ftsg + ((size_t)(b * 8 + g) * HWsz + px) * 8) = v[g];
}

// ---------------------------------------------------------------------------
// MDCN v3: MFMA GEMM. Wave = 16 px x 64 outputs, K=576 over (g,k,c) in 18
// chunks of 32. Lane (lgrp,lane15): bilinear sample for px=lane15 strip,
// gk=chunk*4+lgrp, 8 channels -> one B-fragment. Weights from global in
// A-frag order (coalesced, L2-resident). raw is f32 CHW (coalesced reads).
// ---------------------------------------------------------------------------
__global__ __launch_bounds__(256)
void mdcn_mfma(const ushort* __restrict__ ftsg, const float* __restrict__ rawc,
               const ushort* __restrict__ wmp, const float* __restrict__ db,
               float* __restrict__ out)
{
    const int b    = blockIdx.z;
    const int fidx = (b < 2) ? b : b + 1;
    const int tid  = threadIdx.x;
    const int lane = tid & 63, wid = tid >> 6;
    const int lane15 = lane & 15, lgrp = lane >> 4;
    const int x = blockIdx.x * 16 + lane15;
    const int y = blockIdx.y * 4 + wid;
    const int hw = y * WW + x;

    const float* rawb = rawc + (size_t)b * 216 * HWsz;
    const uint4* wmp4 = (const uint4*)wmp;

    f32x4 acc[4];
#pragma unroll
    for (int m = 0; m < 4; ++m) acc[m] = (f32x4){0.f, 0.f, 0.f, 0.f};

    for (int chunk = 0; chunk < 18; ++chunk) {
        const int gk = chunk * 4 + lgrp;
        const int g  = gk / 9, k = gk - 9 * g;
        const int kyy = k / 3 - 1, kxx = k % 3 - 1;

        const float oy = rawb[(size_t)(g * 18 + 2 * k + 0) * HWsz + hw];
        const float ox = rawb[(size_t)(g * 18 + 2 * k + 1) * HWsz + hw];
        float mv = rawb[(size_t)(144 + g * 9 + k) * HWsz + hw];
        mv = 1.f / (1.f + __expf(-mv));

        const float py = oy + (float)(y + kyy);
        const float px = ox + (float)(x + kxx);
        const float y0f = floorf(py), x0f = floorf(px);
        const float tyf = py - y0f, txf = px - x0f;
        const int y0 = (int)y0f, x0i = (int)x0f;
        const int y1 = y0 + 1, x1 = x0i + 1;
        const bool vy0 = (y0 >= 0) & (y0 < HH);
        const bool vy1 = (y1 >= 0) & (y1 < HH);
        const bool vx0 = (x0i >= 0) & (x0i < WW);
        const bool vx1 = (x1 >= 0) & (x1 < WW);
        const int yc0 = min(max(y0, 0), HH - 1), yc1 = min(max(y1, 0), HH - 1);
        const int xc0 = min(max(x0i, 0), WW - 1), xc1 = min(max(x1, 0), WW - 1);
        float w00 = (1.f - tyf) * (1.f - txf) * mv;
        float w01 = (1.f - tyf) * txf * mv;
        float w10 = tyf * (1.f - txf) * mv;
        float w11 = tyf * txf * mv;
        if (!(vy0 && vx0)) w00 = 0.f;
        if (!(vy0 && vx1)) w01 = 0.f;
        if (!(vy1 && vx0)) w10 = 0.f;
        if (!(vy1 && vx1)) w11 = 0.f;

        const ushort* pb = ftsg + (size_t)(b * 8 + g) * HWsz * 8;
        const uint4 u00 = *(const uint4*)(pb + (size_t)(yc0 * WW + xc0) * 8);
        const uint4 u01 = *(const uint4*)(pb + (size_t)(yc0 * WW + xc1) * 8);
        const uint4 u10 = *(const uint4*)(pb + (size_t)(yc1 * WW + xc0) * 8);
        const uint4 u11 = *(const uint4*)(pb + (size_t)(yc1 * WW + xc1) * 8);
        float f00[8], f01[8], f10[8], f11[8];
        unpk8(u00, f00); unpk8(u01, f01); unpk8(u10, f10); unpk8(u11, f11);

        bf16x8 bfrag;
#pragma unroll
        for (int c = 0; c < 8; ++c) {
            const float v = fmaf(w11, f11[c], fmaf(w10, f10[c],
                             fmaf(w01, f01[c], w00 * f00[c])));
            bfrag[c] = (short)f2bf(v);
        }

#pragma unroll
        for (int mt = 0; mt < 4; ++mt) {
            const bf16x8 a = *(const bf16x8*)&wmp4[(size_t)(chunk * 4 + mt) * 64 + lane];
            acc[mt] = __builtin_amdgcn_mfma_f32_16x16x32_bf16(a, bfrag, acc[mt], 0, 0, 0);
        }
    }

    // D: col = lane15 = px, row = lgrp*4 + reg within each 16-o m-tile.
    float* ob = out + (size_t)fidx * 64 * HWsz + hw;
#pragma unroll
    for (int mt = 0; mt < 4; ++mt) {
        const int o0 = mt * 16 + lgrp * 4;
        const float4 bs = *(const float4*)&db[o0];
        ob[(size_t)(o0 + 0) * HWsz] = acc[mt][0] + bs.x;
        ob[(size_t)(o0 + 1) * HWsz] = acc[mt][1] + bs.y;
        ob[(size_t)(o0 + 2) * HWsz] = acc[mt][2] + bs.z;
        ob[(size_t)(o0 + 3) * HWsz] = acc[mt][3] + bs.w;
    }
}

extern "C" void kernel_launch(void* const* d_in, const int* in_sizes, int n_in,
                              void* d_out, int out_size, void* d_ws, size_t ws_size,
                              hipStream_t stream)
{
    const float* x   = (const float*)d_in[0];
    const float* fw1 = (const float*)d_in[1];
    const float* fb1 = (const float*)d_in[2];
    const float* fw2 = (const float*)d_in[3];
    const float* fb2 = (const float*)d_in[4];
    const float* fw3 = (const float*)d_in[5];
    const float* fb3 = (const float*)d_in[6];
    const float* ow1 = (const float*)d_in[7];
    const float* ob1 = (const float*)d_in[8];
    const float* ow2 = (const float*)d_in[9];
    const float* ob2 = (const float*)d_in[10];
    const float* ow3 = (const float*)d_in[11];
    const float* ob3 = (const float*)d_in[12];
    const float* dw  = (const float*)d_in[13];
    const float* db  = (const float*)d_in[14];
    float* out = (float*)d_out;

    // ---- workspace layout ----
    ushort* buf1 = (ushort*)d_ws;                     // 5*HW*64 bf16
    ushort* buf2 = buf1 + (size_t)5 * HWsz * 64;
    ushort* fts  = buf2 + (size_t)5 * HWsz * 64;
    ushort* ftsg = fts + (size_t)5 * HWsz * 64;       // 4*8*HW*8 bf16
    float*  raw  = (float*)(ftsg + (size_t)4 * 8 * HWsz * 8);  // 4*216*HW f32 (CHW)
    ushort* w2p  = (ushort*)(raw + (size_t)4 * HWsz * 216);
    ushort* w3p  = w2p + 36864;
    ushort* o1p  = w3p + 36864;
    ushort* o2p  = o1p + 73728;
    ushort* o3p  = o2p + 36864;
    ushort* wmp  = o3p + 147456;                      // 18*4*64*8 = 36864 bf16

    const dim3 blk(256);

    // ---- weight packing ----
    pack_weights<<<dim3(18),  blk, 0, stream>>>(fw2, w2p, 64, 64, 4, 2);
    pack_weights<<<dim3(18),  blk, 0, stream>>>(fw3, w3p, 64, 64, 4, 2);
    pack_weights<<<dim3(36),  blk, 0, stream>>>(ow1, o1p, 64, 128, 4, 4);
    pack_weights<<<dim3(18),  blk, 0, stream>>>(ow2, o2p, 64, 64, 4, 2);
    pack_weights<<<dim3(72),  blk, 0, stream>>>(ow3, o3p, 216, 64, 16, 2);
    pack_dw_mfma<<<dim3(18), blk, 0, stream>>>(dw, wmp);

    // ---- feature extraction ----
    conv1_kernel<<<dim3(10, 10, 5), blk, 0, stream>>>(x, fw1, fb1, buf1);
    mfma_conv<8, 2, false, true, 0><<<dim3(5, 20, 5), blk, 0, stream>>>(
        buf1, w2p, fb2, buf2, 64, 4, 1);
    mfma_conv<8, 2, false, true, 0><<<dim3(5, 20, 5), blk, 0, stream>>>(
        buf2, w3p, fb3, fts, 64, 4, 1);

    copy_ref_kernel<<<dim3(100), blk, 0, stream>>>(fts, out);
    repack_feats<<<dim3(100, 4), blk, 0, stream>>>(fts, ftsg);

    // ---- offset network ----
    mfma_conv<4, 4, true, true, 0><<<dim3(5, 40, 4), blk, 0, stream>>>(
        fts, o1p, ob1, buf1, 64, 4, 1);
    mfma_conv<8, 2, false, true, 0><<<dim3(5, 20, 4), blk, 0, stream>>>(
        buf1, o2p, ob2, buf2, 64, 4, 1);
    mfma_conv<8, 2, false, false, 2><<<dim3(5, 20, 16), blk, 0, stream>>>(
        buf2, o3p, ob3, raw, 216, 16, 4);

    // ---- modulated deformable conv + assembly ----
    mdcn_mfma<<<dim3(10, 40, 4), blk, 0, stream>>>(ftsg, raw, wmp, db, out);
}

// Round 5
// 225.956 us; speedup vs baseline: 13.9562x; 1.1529x over previous
//
#include <hip/hip_runtime.h>
#include <hip/hip_bf16.h>
#include <math.h>

#define HH 160
#define WW 160
#define HWsz (HH*WW)

typedef short bf16x8 __attribute__((ext_vector_type(8)));
typedef float f32x4  __attribute__((ext_vector_type(4)));

__device__ inline ushort f2bf(float f) {
    unsigned int u = __float_as_uint(f);
    unsigned int r = (u + 0x7FFFu + ((u >> 16) & 1u)) >> 16;
    return (ushort)r;
}

__device__ inline void unpk8(uint4 u, float* f) {
    f[0] = __uint_as_float(u.x << 16); f[1] = __uint_as_float(u.x & 0xFFFF0000u);
    f[2] = __uint_as_float(u.y << 16); f[3] = __uint_as_float(u.y & 0xFFFF0000u);
    f[4] = __uint_as_float(u.z << 16); f[5] = __uint_as_float(u.z & 0xFFFF0000u);
    f[6] = __uint_as_float(u.w << 16); f[7] = __uint_as_float(u.w & 0xFFFF0000u);
}

// ---------------------------------------------------------------------------
// All conv weights packed in ONE launch. A-fragment order:
// wp[(((tap*CIC + cic)*MT_TOT + mt)*64 + lane)*8 + j],
//   co = mt*16 + (lane&15), ci = cic*32 + (lane>>4)*8 + j.
// ---------------------------------------------------------------------------
__global__ __launch_bounds__(256)
void pack_all(const float* __restrict__ fw2, const float* __restrict__ fw3,
              const float* __restrict__ ow1, const float* __restrict__ ow2,
              const float* __restrict__ ow3,
              ushort* __restrict__ w2p, ushort* __restrict__ w3p,
              ushort* __restrict__ o1p, ushort* __restrict__ o2p,
              ushort* __restrict__ o3p)
{
    const int seg = blockIdx.y;
    const float* w; ushort* wp; int Cout, Cin, MT_TOT, CIC;
    switch (seg) {
        case 0: w = fw2; wp = w2p; Cout = 64;  Cin = 64;  MT_TOT = 4;  CIC = 2; break;
        case 1: w = fw3; wp = w3p; Cout = 64;  Cin = 64;  MT_TOT = 4;  CIC = 2; break;
        case 2: w = ow1; wp = o1p; Cout = 64;  Cin = 128; MT_TOT = 4;  CIC = 4; break;
        case 3: w = ow2; wp = o2p; Cout = 64;  Cin = 64;  MT_TOT = 4;  CIC = 2; break;
        default: w = ow3; wp = o3p; Cout = 216; Cin = 64; MT_TOT = 16; CIC = 2; break;
    }
    const int idx = blockIdx.x * 256 + threadIdx.x;
    const int total = 9 * CIC * MT_TOT * 64;
    if (idx >= total) return;
    const int lane = idx & 63;
    int t = idx >> 6;
    const int mt  = t % MT_TOT; t /= MT_TOT;
    const int cic = t % CIC;    t /= CIC;
    const int tap = t;
    const int co  = mt * 16 + (lane & 15);
    const int ci0 = cic * 32 + (lane >> 4) * 8;
    ushort v[8];
#pragma unroll
    for (int j = 0; j < 8; ++j) {
        const int ci = ci0 + j;
        float f = 0.f;
        if (co < Cout && ci < Cin) f = w[((size_t)co * Cin + ci) * 9 + tap];
        v[j] = f2bf(f);
    }
    uint4 pk;
    pk.x = (unsigned)v[0] | ((unsigned)v[1] << 16);
    pk.y = (unsigned)v[2] | ((unsigned)v[3] << 16);
    pk.z = (unsigned)v[4] | ((unsigned)v[5] << 16);
    pk.w = (unsigned)v[6] | ((unsigned)v[7] << 16);
    *(uint4*)(wp + (size_t)idx * 8) = pk;
}

// dw (64,64,3,3) -> MFMA A-frag order for mdcn GEMM (unchanged).
__global__ __launch_bounds__(256)
void pack_dw_mfma(const float* __restrict__ dw, ushort* __restrict__ wmp)
{
    const int idx = blockIdx.x * 256 + threadIdx.x;
    if (idx >= 18 * 4 * 64) return;
    const int lane = idx & 63;
    const int mt   = (idx >> 6) & 3;
    const int chunk = idx >> 8;
    const int o  = mt * 16 + (lane & 15);
    const int gk = chunk * 4 + (lane >> 4);
    const int g  = gk / 9, k = gk % 9;
    ushort v[8];
#pragma unroll
    for (int j = 0; j < 8; ++j)
        v[j] = f2bf(dw[((size_t)o * 64 + g * 8 + j) * 9 + k]);
    uint4 pk;
    pk.x = (unsigned)v[0] | ((unsigned)v[1] << 16);
    pk.y = (unsigned)v[2] | ((unsigned)v[3] << 16);
    pk.z = (unsigned)v[4] | ((unsigned)v[5] << 16);
    pk.w = (unsigned)v[6] | ((unsigned)v[7] << 16);
    *(uint4*)(wmp + (size_t)idx * 8) = pk;
}

// ---------------------------------------------------------------------------
// MFMA implicit-GEMM 3x3 SAME conv, barrier-free K-loop.
// Block 256 thr = 4 waves; block tile 64co x (8 rows x 32) px; wave tile
// 64co x 64px (4 m-tiles x 4 n-tiles). A-fragments loaded per (tap,cic)
// straight from global (coalesced 16B/lane, L1/L2-hot) -> NO weight LDS,
// NO K-loop barriers. Input staged once per ci-step (CI_STEPS for Cin>64).
// OMODE: 0 = bf16 NHWC, 2 = f32 CHW.
// ---------------------------------------------------------------------------
template<int CIC_TILE, int CI_STEPS, bool CONCAT, bool RELU, int OMODE>
__global__ __launch_bounds__(256, 3)
void mfma_conv(const ushort* __restrict__ in, const ushort* __restrict__ wp,
               const float* __restrict__ bias, void* __restrict__ outv,
               int Cout, int MT_TOT, int COG)
{
    constexpr int ROWS = 8, HR = ROWS + 2, NT = 4;
    constexpr int C8   = CIC_TILE * 4;            // 16B chunks per px per stage
    constexpr int CICT = CIC_TILE * CI_STEPS;     // total 32-ci chunks
    constexpr int CIN  = CICT * 32;
    __shared__ uint4 s_in4[HR * 34 * C8];         // 43520 B

    const int tid = threadIdx.x;
    const int lane = tid & 63, wid = tid >> 6;
    const int lane15 = lane & 15, lgrp = lane >> 4;
    const int bz = blockIdx.z;
    const int frame = bz / COG, cog = bz % COG;
    const int x0 = blockIdx.x * 32, y0 = blockIdx.y * ROWS;

    const ushort* src = nullptr; const ushort* srcRef = nullptr; const ushort* srcCur = nullptr;
    if (CONCAT) {
        const int fidx = (frame < 2) ? frame : frame + 1;
        srcRef = in + (size_t)2 * HWsz * 64;
        srcCur = in + (size_t)fidx * HWsz * 64;
    } else {
        src = in + (size_t)frame * HWsz * CIN;
    }

    f32x4 acc[4][NT];
#pragma unroll
    for (int m = 0; m < 4; ++m)
#pragma unroll
        for (int n = 0; n < NT; ++n) acc[m][n] = (f32x4){0.f, 0.f, 0.f, 0.f};

    const uint4* wp4 = (const uint4*)wp;
    const int wrow = wid * 2;
    const int mtg0 = cog * 4;

    for (int step = 0; step < CI_STEPS; ++step) {
        if (step) __syncthreads();   // protect s_in4 overwrite
        // ---- stage this ci-step's input halo tile ----
        for (int i = tid; i < HR * 34 * C8; i += 256) {
            const int ci8l = i & (C8 - 1);
            const int rem = i / C8;
            const int col = rem % 34, row = rem / 34;
            const int gy = y0 + row - 1, gx = x0 + col - 1;
            const int gci8 = step * C8 + ci8l;
            uint4 v = {0u, 0u, 0u, 0u};
            if (gy >= 0 && gy < HH && gx >= 0 && gx < WW) {
                if (CONCAT) {
                    const ushort* sp = (gci8 < 8) ? srcRef : srcCur;
                    v = *(const uint4*)(sp + (size_t)(gy * WW + gx) * 64 + (gci8 & 7) * 8);
                } else {
                    v = *(const uint4*)(src + (size_t)(gy * WW + gx) * CIN + gci8 * 8);
                }
            }
            s_in4[(row * 34 + col) * C8 + (ci8l ^ (col & 7))] = v;
        }
        __syncthreads();

        // ---- barrier-free K-loop: 9 taps x CIC_TILE chunks ----
#pragma unroll 3
        for (int tap = 0; tap < 9; ++tap) {
            const int dy  = tap / 3 - 1;
            const int dxp = tap % 3;
#pragma unroll
            for (int cic = 0; cic < CIC_TILE; ++cic) {
                const uint4* ap = wp4 +
                    ((size_t)(tap * CICT + step * CIC_TILE + cic) * MT_TOT + mtg0) * 64 + lane;
                bf16x8 a[4];
#pragma unroll
                for (int mt = 0; mt < 4; ++mt)
                    a[mt] = *(const bf16x8*)(ap + (size_t)mt * 64);
#pragma unroll
                for (int nt = 0; nt < NT; ++nt) {
                    const int row_l = wrow + (nt >> 1) + dy + 1;
                    const int col_l = (nt & 1) * 16 + lane15 + dxp;
                    const bf16x8 b = *(const bf16x8*)
                        &s_in4[(row_l * 34 + col_l) * C8 + ((cic * 4 + lgrp) ^ (col_l & 7))];
#pragma unroll
                    for (int mt = 0; mt < 4; ++mt)
                        acc[mt][nt] = __builtin_amdgcn_mfma_f32_16x16x32_bf16(a[mt], b, acc[mt][nt], 0, 0, 0);
                }
            }
        }
    }

    // ---- epilogue: D row = co (lgrp*4+reg), col = px (lane15) ----
#pragma unroll
    for (int mt = 0; mt < 4; ++mt) {
        const int co = cog * 64 + mt * 16 + lgrp * 4;
        if (co < Cout) {
            const float4 bs = *(const float4*)&bias[co];
#pragma unroll
            for (int nt = 0; nt < NT; ++nt) {
                const int yy = y0 + wrow + (nt >> 1);
                const int xx = x0 + (nt & 1) * 16 + lane15;
                f32x4 v = acc[mt][nt];
                v[0] += bs.x; v[1] += bs.y; v[2] += bs.z; v[3] += bs.w;
                if (RELU) {
                    v[0] = fmaxf(v[0], 0.f); v[1] = fmaxf(v[1], 0.f);
                    v[2] = fmaxf(v[2], 0.f); v[3] = fmaxf(v[3], 0.f);
                }
                if (OMODE == 0) {
                    const size_t po = ((size_t)frame * HWsz + yy * WW + xx) * (size_t)Cout + co;
                    uint2 pk;
                    pk.x = (unsigned)f2bf(v[0]) | ((unsigned)f2bf(v[1]) << 16);
                    pk.y = (unsigned)f2bf(v[2]) | ((unsigned)f2bf(v[3]) << 16);
                    *(uint2*)((ushort*)outv + po) = pk;
                } else {
                    float* of = (float*)outv;
                    const size_t base = ((size_t)frame * Cout + co) * HWsz + yy * WW + xx;
#pragma unroll
                    for (int j = 0; j < 4; ++j)
                        of[base + (size_t)j * HWsz] = v[j];
                }
            }
        }
    }
}

// ---------------------------------------------------------------------------
// conv1 (unchanged).
// ---------------------------------------------------------------------------
__global__ __launch_bounds__(256)
void conv1_kernel(const float* __restrict__ x, const float* __restrict__ w,
                  const float* __restrict__ b, ushort* __restrict__ out)
{
    const int fr = blockIdx.z;
    const int t = threadIdx.x;
    const int tx = t & 15, ty = t >> 4;
    const int x0 = blockIdx.x * 16, y0 = blockIdx.y * 16;

    __shared__ float s_x[4][18][18];
    __shared__ float s_w[36][64];
    __shared__ float s_b[64];

    for (int i = t; i < 4 * 18 * 18; i += 256) {
        const int ci = i / 324, rem = i % 324;
        const int yy = rem / 18, xx = rem % 18;
        const int gy = y0 + yy - 1, gx = x0 + xx - 1;
        float v = 0.f;
        if (gy >= 0 && gy < HH && gx >= 0 && gx < WW)
            v = x[((size_t)fr * 4 + ci) * HWsz + gy * WW + gx];
        s_x[ci][yy][xx] = v;
    }
    for (int i = t; i < 36 * 64; i += 256) {
        const int row = i / 64, o = i % 64;
        const int ci = row / 9, tap = row % 9;
        s_w[row][o] = w[((size_t)o * 4 + ci) * 9 + tap];
    }
    if (t < 64) s_b[t] = b[t];
    __syncthreads();

    float acc[64];
#pragma unroll
    for (int i = 0; i < 64; ++i) acc[i] = 0.f;

#pragma unroll
    for (int ci = 0; ci < 4; ++ci) {
#pragma unroll
        for (int tap = 0; tap < 9; ++tap) {
            const float v = s_x[ci][ty + tap / 3][tx + tap % 3];
            const float4* wr = (const float4*)&s_w[ci * 9 + tap][0];
#pragma unroll
            for (int o4 = 0; o4 < 16; ++o4) {
                const float4 wv = wr[o4];
                acc[o4 * 4 + 0] = fmaf(v, wv.x, acc[o4 * 4 + 0]);
                acc[o4 * 4 + 1] = fmaf(v, wv.y, acc[o4 * 4 + 1]);
                acc[o4 * 4 + 2] = fmaf(v, wv.z, acc[o4 * 4 + 2]);
                acc[o4 * 4 + 3] = fmaf(v, wv.w, acc[o4 * 4 + 3]);
            }
        }
    }

    ushort* ob = out + ((size_t)fr * HWsz + (y0 + ty) * WW + (x0 + tx)) * 64;
#pragma unroll
    for (int o8 = 0; o8 < 8; ++o8) {
        ushort v[8];
#pragma unroll
        for (int j = 0; j < 8; ++j)
            v[j] = f2bf(fmaxf(acc[o8 * 8 + j] + s_b[o8 * 8 + j], 0.f));
        uint4 pk;
        pk.x = (unsigned)v[0] | ((unsigned)v[1] << 16);
        pk.y = (unsigned)v[2] | ((unsigned)v[3] << 16);
        pk.z = (unsigned)v[4] | ((unsigned)v[5] << 16);
        pk.w = (unsigned)v[6] | ((unsigned)v[7] << 16);
        *(uint4*)(ob + o8 * 8) = pk;
    }
}

// feats[2] NHWC bf16 -> out frame 2 NCHW f32
__global__ __launch_bounds__(256)
void copy_ref_kernel(const ushort* __restrict__ fts, float* __restrict__ out)
{
    const int px = blockIdx.x * 256 + threadIdx.x;
    if (px >= HWsz) return;
    const uint4* p = (const uint4*)(fts + ((size_t)2 * HWsz + px) * 64);
    float* ob = out + (size_t)2 * 64 * HWsz + px;
#pragma unroll
    for (int o8 = 0; o8 < 8; ++o8) {
        float f[8];
        unpk8(p[o8], f);
#pragma unroll
        for (int j = 0; j < 8; ++j)
            ob[(size_t)(o8 * 8 + j) * HWsz] = f[j];
    }
}

// fts NHWC64 -> group-major ftsg[(b,g,hw,8ch)] for the 4 non-center frames.
__global__ __launch_bounds__(256)
void repack_feats(const ushort* __restrict__ fts, ushort* __restrict__ ftsg)
{
    const int px = blockIdx.x * 256 + threadIdx.x;
    const int b  = blockIdx.y;
    if (px >= HWsz) return;
    const int fidx = (b < 2) ? b : b + 1;
    const uint4* src = (const uint4*)(fts + ((size_t)fidx * HWsz + px) * 64);
    uint4 v[8];
#pragma unroll
    for (int g = 0; g < 8; ++g) v[g] = src[g];
#pragma unroll
    for (int g = 0; g < 8; ++g)
        *(uint4*)(ftsg + ((size_t)(b * 8 + g) * HWsz + px) * 8) = v[g];
}

// ---------------------------------------------------------------------------
// MDCN MFMA GEMM (unchanged from round 4).
// ---------------------------------------------------------------------------
__global__ __launch_bounds__(256)
void mdcn_mfma(const ushort* __restrict__ ftsg, const float* __restrict__ rawc,
               const ushort* __restrict__ wmp, const float* __restrict__ db,
               float* __restrict__ out)
{
    const int b    = blockIdx.z;
    const int fidx = (b < 2) ? b : b + 1;
    const int tid  = threadIdx.x;
    const int lane = tid & 63, wid = tid >> 6;
    const int lane15 = lane & 15, lgrp = lane >> 4;
    const int x = blockIdx.x * 16 + lane15;
    const int y = blockIdx.y * 4 + wid;
    const int hw = y * WW + x;

    const float* rawb = rawc + (size_t)b * 216 * HWsz;
    const uint4* wmp4 = (const uint4*)wmp;

    f32x4 acc[4];
#pragma unroll
    for (int m = 0; m < 4; ++m) acc[m] = (f32x4){0.f, 0.f, 0.f, 0.f};

    for (int chunk = 0; chunk < 18; ++chunk) {
        const int gk = chunk * 4 + lgrp;
        const int g  = gk / 9, k = gk - 9 * g;
        const int kyy = k / 3 - 1, kxx = k % 3 - 1;

        const float oy = rawb[(size_t)(g * 18 + 2 * k + 0) * HWsz + hw];
        const float ox = rawb[(size_t)(g * 18 + 2 * k + 1) * HWsz + hw];
        float mv = rawb[(size_t)(144 + g * 9 + k) * HWsz + hw];
        mv = 1.f / (1.f + __expf(-mv));

        const float py = oy + (float)(y + kyy);
        const float px = ox + (float)(x + kxx);
        const float y0f = floorf(py), x0f = floorf(px);
        const float tyf = py - y0f, txf = px - x0f;
        const int y0 = (int)y0f, x0i = (int)x0f;
        const int y1 = y0 + 1, x1 = x0i + 1;
        const bool vy0 = (y0 >= 0) & (y0 < HH);
        const bool vy1 = (y1 >= 0) & (y1 < HH);
        const bool vx0 = (x0i >= 0) & (x0i < WW);
        const bool vx1 = (x1 >= 0) & (x1 < WW);
        const int yc0 = min(max(y0, 0), HH - 1), yc1 = min(max(y1, 0), HH - 1);
        const int xc0 = min(max(x0i, 0), WW - 1), xc1 = min(max(x1, 0), WW - 1);
        float w00 = (1.f - tyf) * (1.f - txf) * mv;
        float w01 = (1.f - tyf) * txf * mv;
        float w10 = tyf * (1.f - txf) * mv;
        float w11 = tyf * txf * mv;
        if (!(vy0 && vx0)) w00 = 0.f;
        if (!(vy0 && vx1)) w01 = 0.f;
        if (!(vy1 && vx0)) w10 = 0.f;
        if (!(vy1 && vx1)) w11 = 0.f;

        const ushort* pb = ftsg + (size_t)(b * 8 + g) * HWsz * 8;
        const uint4 u00 = *(const uint4*)(pb + (size_t)(yc0 * WW + xc0) * 8);
        const uint4 u01 = *(const uint4*)(pb + (size_t)(yc0 * WW + xc1) * 8);
        const uint4 u10 = *(const uint4*)(pb + (size_t)(yc1 * WW + xc0) * 8);
        const uint4 u11 = *(const uint4*)(pb + (size_t)(yc1 * WW + xc1) * 8);
        float f00[8], f01[8], f10[8], f11[8];
        unpk8(u00, f00); unpk8(u01, f01); unpk8(u10, f10); unpk8(u11, f11);

        bf16x8 bfrag;
#pragma unroll
        for (int c = 0; c < 8; ++c) {
            const float v = fmaf(w11, f11[c], fmaf(w10, f10[c],
                             fmaf(w01, f01[c], w00 * f00[c])));
            bfrag[c] = (short)f2bf(v);
        }

#pragma unroll
        for (int mt = 0; mt < 4; ++mt) {
            const bf16x8 a = *(const bf16x8*)&wmp4[(size_t)(chunk * 4 + mt) * 64 + lane];
            acc[mt] = __builtin_amdgcn_mfma_f32_16x16x32_bf16(a, bfrag, acc[mt], 0, 0, 0);
        }
    }

    float* ob = out + (size_t)fidx * 64 * HWsz + hw;
#pragma unroll
    for (int mt = 0; mt < 4; ++mt) {
        const int o0 = mt * 16 + lgrp * 4;
        const float4 bs = *(const float4*)&db[o0];
        ob[(size_t)(o0 + 0) * HWsz] = acc[mt][0] + bs.x;
        ob[(size_t)(o0 + 1) * HWsz] = acc[mt][1] + bs.y;
        ob[(size_t)(o0 + 2) * HWsz] = acc[mt][2] + bs.z;
        ob[(size_t)(o0 + 3) * HWsz] = acc[mt][3] + bs.w;
    }
}

extern "C" void kernel_launch(void* const* d_in, const int* in_sizes, int n_in,
                              void* d_out, int out_size, void* d_ws, size_t ws_size,
                              hipStream_t stream)
{
    const float* x   = (const float*)d_in[0];
    const float* fw1 = (const float*)d_in[1];
    const float* fb1 = (const float*)d_in[2];
    const float* fw2 = (const float*)d_in[3];
    const float* fb2 = (const float*)d_in[4];
    const float* fw3 = (const float*)d_in[5];
    const float* fb3 = (const float*)d_in[6];
    const float* ow1 = (const float*)d_in[7];
    const float* ob1 = (const float*)d_in[8];
    const float* ow2 = (const float*)d_in[9];
    const float* ob2 = (const float*)d_in[10];
    const float* ow3 = (const float*)d_in[11];
    const float* ob3 = (const float*)d_in[12];
    const float* dw  = (const float*)d_in[13];
    const float* db  = (const float*)d_in[14];
    float* out = (float*)d_out;

    // ---- workspace layout ----
    ushort* buf1 = (ushort*)d_ws;                     // 5*HW*64 bf16
    ushort* buf2 = buf1 + (size_t)5 * HWsz * 64;
    ushort* fts  = buf2 + (size_t)5 * HWsz * 64;
    ushort* ftsg = fts + (size_t)5 * HWsz * 64;       // 4*8*HW*8 bf16
    float*  raw  = (float*)(ftsg + (size_t)4 * 8 * HWsz * 8);  // 4*216*HW f32 (CHW)
    ushort* w2p  = (ushort*)(raw + (size_t)4 * HWsz * 216);
    ushort* w3p  = w2p + 36864;
    ushort* o1p  = w3p + 36864;
    ushort* o2p  = o1p + 73728;
    ushort* o3p  = o2p + 36864;
    ushort* wmp  = o3p + 147456;                      // 18*4*64*8 = 36864 bf16

    const dim3 blk(256);

    // ---- weight packing (2 launches) ----
    pack_all<<<dim3(72, 5), blk, 0, stream>>>(fw2, fw3, ow1, ow2, ow3,
                                              w2p, w3p, o1p, o2p, o3p);
    pack_dw_mfma<<<dim3(18), blk, 0, stream>>>(dw, wmp);

    // ---- feature extraction ----
    conv1_kernel<<<dim3(10, 10, 5), blk, 0, stream>>>(x, fw1, fb1, buf1);
    mfma_conv<2, 1, false, true, 0><<<dim3(5, 20, 5), blk, 0, stream>>>(
        buf1, w2p, fb2, buf2, 64, 4, 1);
    mfma_conv<2, 1, false, true, 0><<<dim3(5, 20, 5), blk, 0, stream>>>(
        buf2, w3p, fb3, fts, 64, 4, 1);

    copy_ref_kernel<<<dim3(100), blk, 0, stream>>>(fts, out);
    repack_feats<<<dim3(100, 4), blk, 0, stream>>>(fts, ftsg);

    // ---- offset network ----
    mfma_conv<2, 2, true, true, 0><<<dim3(5, 20, 4), blk, 0, stream>>>(
        fts, o1p, ob1, buf1, 64, 4, 1);
    mfma_conv<2, 1, false, true, 0><<<dim3(5, 20, 4), blk, 0, stream>>>(
        buf1, o2p, ob2, buf2, 64, 4, 1);
    mfma_conv<2, 1, false, false, 2><<<dim3(5, 20, 16), blk, 0, stream>>>(
        buf2, o3p, ob3, raw, 216, 16, 4);

    // ---- modulated deformable conv + assembly ----
    mdcn_mfma<<<dim3(10, 40, 4), blk, 0, stream>>>(ftsg, raw, wmp, db, out);
}

// Round 6
// 216.565 us; speedup vs baseline: 14.5614x; 1.0434x over previous
//
#include <hip/hip_runtime.h>
#include <hip/hip_bf16.h>
#include <math.h>

#define HH 160
#define WW 160
#define HWsz (HH*WW)

typedef short bf16x8 __attribute__((ext_vector_type(8)));
typedef float f32x4  __attribute__((ext_vector_type(4)));

__device__ inline ushort f2bf(float f) {
    unsigned int u = __float_as_uint(f);
    unsigned int r = (u + 0x7FFFu + ((u >> 16) & 1u)) >> 16;
    return (ushort)r;
}

__device__ inline void unpk8(uint4 u, float* f) {
    f[0] = __uint_as_float(u.x << 16); f[1] = __uint_as_float(u.x & 0xFFFF0000u);
    f[2] = __uint_as_float(u.y << 16); f[3] = __uint_as_float(u.y & 0xFFFF0000u);
    f[4] = __uint_as_float(u.z << 16); f[5] = __uint_as_float(u.z & 0xFFFF0000u);
    f[6] = __uint_as_float(u.w << 16); f[7] = __uint_as_float(u.w & 0xFFFF0000u);
}

// ---------------------------------------------------------------------------
// ALL weight packing in one launch. Segments 0..4: conv A-fragment order
// wp[(((tap*CIC+cic)*MT_TOT+mt)*64+lane)*8+j], co=mt*16+(lane&15),
// ci=cic*32+(lane>>4)*8+j. Segment 5: mdcn dw A-frag order (K=(g,k,c)).
// ---------------------------------------------------------------------------
__global__ __launch_bounds__(256)
void pack_all(const float* __restrict__ fw2, const float* __restrict__ fw3,
              const float* __restrict__ ow1, const float* __restrict__ ow2,
              const float* __restrict__ ow3, const float* __restrict__ dw,
              ushort* __restrict__ w2p, ushort* __restrict__ w3p,
              ushort* __restrict__ o1p, ushort* __restrict__ o2p,
              ushort* __restrict__ o3p, ushort* __restrict__ wmp)
{
    const int seg = blockIdx.y;
    const int idx = blockIdx.x * 256 + threadIdx.x;

    if (seg == 5) {   // mdcn weights
        if (idx >= 18 * 4 * 64) return;
        const int lane = idx & 63;
        const int mt   = (idx >> 6) & 3;
        const int chunk = idx >> 8;
        const int o  = mt * 16 + (lane & 15);
        const int gk = chunk * 4 + (lane >> 4);
        const int g  = gk / 9, k = gk % 9;
        ushort v[8];
#pragma unroll
        for (int j = 0; j < 8; ++j)
            v[j] = f2bf(dw[((size_t)o * 64 + g * 8 + j) * 9 + k]);
        uint4 pk;
        pk.x = (unsigned)v[0] | ((unsigned)v[1] << 16);
        pk.y = (unsigned)v[2] | ((unsigned)v[3] << 16);
        pk.z = (unsigned)v[4] | ((unsigned)v[5] << 16);
        pk.w = (unsigned)v[6] | ((unsigned)v[7] << 16);
        *(uint4*)(wmp + (size_t)idx * 8) = pk;
        return;
    }

    const float* w; ushort* wp; int Cout, Cin, MT_TOT, CIC;
    switch (seg) {
        case 0: w = fw2; wp = w2p; Cout = 64;  Cin = 64;  MT_TOT = 4;  CIC = 2; break;
        case 1: w = fw3; wp = w3p; Cout = 64;  Cin = 64;  MT_TOT = 4;  CIC = 2; break;
        case 2: w = ow1; wp = o1p; Cout = 64;  Cin = 128; MT_TOT = 4;  CIC = 4; break;
        case 3: w = ow2; wp = o2p; Cout = 64;  Cin = 64;  MT_TOT = 4;  CIC = 2; break;
        default: w = ow3; wp = o3p; Cout = 216; Cin = 64; MT_TOT = 16; CIC = 2; break;
    }
    const int total = 9 * CIC * MT_TOT * 64;
    if (idx >= total) return;
    const int lane = idx & 63;
    int t = idx >> 6;
    const int mt  = t % MT_TOT; t /= MT_TOT;
    const int cic = t % CIC;    t /= CIC;
    const int tap = t;
    const int co  = mt * 16 + (lane & 15);
    const int ci0 = cic * 32 + (lane >> 4) * 8;
    ushort v[8];
#pragma unroll
    for (int j = 0; j < 8; ++j) {
        const int ci = ci0 + j;
        float f = 0.f;
        if (co < Cout && ci < Cin) f = w[((size_t)co * Cin + ci) * 9 + tap];
        v[j] = f2bf(f);
    }
    uint4 pk;
    pk.x = (unsigned)v[0] | ((unsigned)v[1] << 16);
    pk.y = (unsigned)v[2] | ((unsigned)v[3] << 16);
    pk.z = (unsigned)v[4] | ((unsigned)v[5] << 16);
    pk.w = (unsigned)v[6] | ((unsigned)v[7] << 16);
    *(uint4*)(wp + (size_t)idx * 8) = pk;
}

// ---------------------------------------------------------------------------
// MFMA implicit-GEMM 3x3 SAME conv, barrier-free K-loop (round-5 structure).
// OMODE: 0 = bf16 NHWC; 1 = bf16 NHWC + fused ref-copy/ftsg-repack writes;
//        3 = packed raw ushort4{oy,ox,m,pad} per (gk,px) for mdcn.
// ---------------------------------------------------------------------------
template<int CIC_TILE, int CI_STEPS, bool CONCAT, bool RELU, int OMODE>
__global__ __launch_bounds__(256, 3)
void mfma_conv(const ushort* __restrict__ in, const ushort* __restrict__ wp,
               const float* __restrict__ bias, void* __restrict__ outv,
               int Cout, int MT_TOT, int COG,
               float* __restrict__ outmain, ushort* __restrict__ ftsg)
{
    constexpr int ROWS = 8, HR = ROWS + 2, NT = 4;
    constexpr int C8   = CIC_TILE * 4;
    constexpr int CICT = CIC_TILE * CI_STEPS;
    constexpr int CIN  = CICT * 32;
    __shared__ uint4 s_in4[HR * 34 * C8];

    const int tid = threadIdx.x;
    const int lane = tid & 63, wid = tid >> 6;
    const int lane15 = lane & 15, lgrp = lane >> 4;
    const int bz = blockIdx.z;
    const int frame = bz / COG, cog = bz % COG;
    const int x0 = blockIdx.x * 32, y0 = blockIdx.y * ROWS;

    const ushort* src = nullptr; const ushort* srcRef = nullptr; const ushort* srcCur = nullptr;
    if (CONCAT) {
        const int fidx = (frame < 2) ? frame : frame + 1;
        srcRef = in + (size_t)2 * HWsz * 64;
        srcCur = in + (size_t)fidx * HWsz * 64;
    } else {
        src = in + (size_t)frame * HWsz * CIN;
    }

    f32x4 acc[4][NT];
#pragma unroll
    for (int m = 0; m < 4; ++m)
#pragma unroll
        for (int n = 0; n < NT; ++n) acc[m][n] = (f32x4){0.f, 0.f, 0.f, 0.f};

    const uint4* wp4 = (const uint4*)wp;
    const int wrow = wid * 2;
    const int mtg0 = cog * 4;

    for (int step = 0; step < CI_STEPS; ++step) {
        if (step) __syncthreads();
        for (int i = tid; i < HR * 34 * C8; i += 256) {
            const int ci8l = i & (C8 - 1);
            const int rem = i / C8;
            const int col = rem % 34, row = rem / 34;
            const int gy = y0 + row - 1, gx = x0 + col - 1;
            const int gci8 = step * C8 + ci8l;
            uint4 v = {0u, 0u, 0u, 0u};
            if (gy >= 0 && gy < HH && gx >= 0 && gx < WW) {
                if (CONCAT) {
                    const ushort* sp = (gci8 < 8) ? srcRef : srcCur;
                    v = *(const uint4*)(sp + (size_t)(gy * WW + gx) * 64 + (gci8 & 7) * 8);
                } else {
                    v = *(const uint4*)(src + (size_t)(gy * WW + gx) * CIN + gci8 * 8);
                }
            }
            s_in4[(row * 34 + col) * C8 + (ci8l ^ (col & 7))] = v;
        }
        __syncthreads();

#pragma unroll 3
        for (int tap = 0; tap < 9; ++tap) {
            const int dy  = tap / 3 - 1;
            const int dxp = tap % 3;
#pragma unroll
            for (int cic = 0; cic < CIC_TILE; ++cic) {
                const uint4* ap = wp4 +
                    ((size_t)(tap * CICT + step * CIC_TILE + cic) * MT_TOT + mtg0) * 64 + lane;
                bf16x8 a[4];
#pragma unroll
                for (int mt = 0; mt < 4; ++mt)
                    a[mt] = *(const bf16x8*)(ap + (size_t)mt * 64);
#pragma unroll
                for (int nt = 0; nt < NT; ++nt) {
                    const int row_l = wrow + (nt >> 1) + dy + 1;
                    const int col_l = (nt & 1) * 16 + lane15 + dxp;
                    const bf16x8 b = *(const bf16x8*)
                        &s_in4[(row_l * 34 + col_l) * C8 + ((cic * 4 + lgrp) ^ (col_l & 7))];
#pragma unroll
                    for (int mt = 0; mt < 4; ++mt)
                        acc[mt][nt] = __builtin_amdgcn_mfma_f32_16x16x32_bf16(a[mt], b, acc[mt][nt], 0, 0, 0);
                }
            }
        }
    }

    // ---- epilogue ----
#pragma unroll
    for (int mt = 0; mt < 4; ++mt) {
        const int co = cog * 64 + mt * 16 + lgrp * 4;
        if (co < Cout) {
            const float4 bs = *(const float4*)&bias[co];
#pragma unroll
            for (int nt = 0; nt < NT; ++nt) {
                const int yy = y0 + wrow + (nt >> 1);
                const int xx = x0 + (nt & 1) * 16 + lane15;
                const int hw = yy * WW + xx;
                f32x4 v = acc[mt][nt];
                v[0] += bs.x; v[1] += bs.y; v[2] += bs.z; v[3] += bs.w;
                if (RELU) {
                    v[0] = fmaxf(v[0], 0.f); v[1] = fmaxf(v[1], 0.f);
                    v[2] = fmaxf(v[2], 0.f); v[3] = fmaxf(v[3], 0.f);
                }
                if (OMODE <= 1) {
                    uint2 pk;
                    pk.x = (unsigned)f2bf(v[0]) | ((unsigned)f2bf(v[1]) << 16);
                    pk.y = (unsigned)f2bf(v[2]) | ((unsigned)f2bf(v[3]) << 16);
                    *(uint2*)((ushort*)outv + ((size_t)frame * HWsz + hw) * 64 + co) = pk;
                    if (OMODE == 1) {
                        if (frame == 2) {
                            // ref frame -> main output, f32 CHW
#pragma unroll
                            for (int j = 0; j < 4; ++j)
                                outmain[((size_t)(128 + co + j)) * HWsz + hw] = v[j];
                        } else {
                            const int b = (frame < 2) ? frame : frame - 1;
                            *(uint2*)(ftsg + (((size_t)(b * 8 + (co >> 3)) * HWsz + hw) * 8 + (co & 7))) = pk;
                        }
                    }
                } else {
                    // OMODE==3: packed raw ushort4{oy,ox,m,pad} per (gk,px)
                    ushort* rawp = (ushort*)outv + (size_t)frame * 72 * HWsz * 4;
                    const ushort h0 = f2bf(v[0]), h1 = f2bf(v[1]);
                    const ushort h2 = f2bf(v[2]), h3 = f2bf(v[3]);
                    if (co < 144) {
                        // offset channels: co=g*18+k*2+comp -> gk=co>>1
                        *(unsigned*)(rawp + ((size_t)(co >> 1) * HWsz + hw) * 4) =
                            (unsigned)h0 | ((unsigned)h1 << 16);
                        *(unsigned*)(rawp + ((size_t)((co >> 1) + 1) * HWsz + hw) * 4) =
                            (unsigned)h2 | ((unsigned)h3 << 16);
                    } else {
                        const int gk0 = co - 144;   // mask channels
                        rawp[((size_t)(gk0 + 0) * HWsz + hw) * 4 + 2] = h0;
                        rawp[((size_t)(gk0 + 1) * HWsz + hw) * 4 + 2] = h1;
                        rawp[((size_t)(gk0 + 2) * HWsz + hw) * 4 + 2] = h2;
                        rawp[((size_t)(gk0 + 3) * HWsz + hw) * 4 + 2] = h3;
                    }
                }
            }
        }
    }
}

// ---------------------------------------------------------------------------
// conv1: Cin=4 NCHW f32 -> 64ch NHWC bf16 (unchanged).
// ---------------------------------------------------------------------------
__global__ __launch_bounds__(256)
void conv1_kernel(const float* __restrict__ x, const float* __restrict__ w,
                  const float* __restrict__ b, ushort* __restrict__ out)
{
    const int fr = blockIdx.z;
    const int t = threadIdx.x;
    const int tx = t & 15, ty = t >> 4;
    const int x0 = blockIdx.x * 16, y0 = blockIdx.y * 16;

    __shared__ float s_x[4][18][18];
    __shared__ float s_w[36][64];
    __shared__ float s_b[64];

    for (int i = t; i < 4 * 18 * 18; i += 256) {
        const int ci = i / 324, rem = i % 324;
        const int yy = rem / 18, xx = rem % 18;
        const int gy = y0 + yy - 1, gx = x0 + xx - 1;
        float v = 0.f;
        if (gy >= 0 && gy < HH && gx >= 0 && gx < WW)
            v = x[((size_t)fr * 4 + ci) * HWsz + gy * WW + gx];
        s_x[ci][yy][xx] = v;
    }
    for (int i = t; i < 36 * 64; i += 256) {
        const int row = i / 64, o = i % 64;
        const int ci = row / 9, tap = row % 9;
        s_w[row][o] = w[((size_t)o * 4 + ci) * 9 + tap];
    }
    if (t < 64) s_b[t] = b[t];
    __syncthreads();

    float acc[64];
#pragma unroll
    for (int i = 0; i < 64; ++i) acc[i] = 0.f;

#pragma unroll
    for (int ci = 0; ci < 4; ++ci) {
#pragma unroll
        for (int tap = 0; tap < 9; ++tap) {
            const float v = s_x[ci][ty + tap / 3][tx + tap % 3];
            const float4* wr = (const float4*)&s_w[ci * 9 + tap][0];
#pragma unroll
            for (int o4 = 0; o4 < 16; ++o4) {
                const float4 wv = wr[o4];
                acc[o4 * 4 + 0] = fmaf(v, wv.x, acc[o4 * 4 + 0]);
                acc[o4 * 4 + 1] = fmaf(v, wv.y, acc[o4 * 4 + 1]);
                acc[o4 * 4 + 2] = fmaf(v, wv.z, acc[o4 * 4 + 2]);
                acc[o4 * 4 + 3] = fmaf(v, wv.w, acc[o4 * 4 + 3]);
            }
        }
    }

    ushort* ob = out + ((size_t)fr * HWsz + (y0 + ty) * WW + (x0 + tx)) * 64;
#pragma unroll
    for (int o8 = 0; o8 < 8; ++o8) {
        ushort v[8];
#pragma unroll
        for (int j = 0; j < 8; ++j)
            v[j] = f2bf(fmaxf(acc[o8 * 8 + j] + s_b[o8 * 8 + j], 0.f));
        uint4 pk;
        pk.x = (unsigned)v[0] | ((unsigned)v[1] << 16);
        pk.y = (unsigned)v[2] | ((unsigned)v[3] << 16);
        pk.z = (unsigned)v[4] | ((unsigned)v[5] << 16);
        pk.w = (unsigned)v[6] | ((unsigned)v[7] << 16);
        *(uint4*)(ob + o8 * 8) = pk;
    }
}

// ---------------------------------------------------------------------------
// MDCN MFMA GEMM v4: packed bf16 raw (one 8B load per chunk), cvt_pk pack.
// ---------------------------------------------------------------------------
__global__ __launch_bounds__(256)
void mdcn_mfma(const ushort* __restrict__ ftsg, const ushort* __restrict__ rawpk,
               const ushort* __restrict__ wmp, const float* __restrict__ db,
               float* __restrict__ out)
{
    const int b    = blockIdx.z;
    const int fidx = (b < 2) ? b : b + 1;
    const int tid  = threadIdx.x;
    const int lane = tid & 63, wid = tid >> 6;
    const int lane15 = lane & 15, lgrp = lane >> 4;
    const int x = blockIdx.x * 16 + lane15;
    const int y = blockIdx.y * 4 + wid;
    const int hw = y * WW + x;

    const ushort* rawb = rawpk + (size_t)b * 72 * HWsz * 4;
    const uint4* wmp4 = (const uint4*)wmp;

    f32x4 acc[4];
#pragma unroll
    for (int m = 0; m < 4; ++m) acc[m] = (f32x4){0.f, 0.f, 0.f, 0.f};

#pragma unroll 2
    for (int chunk = 0; chunk < 18; ++chunk) {
        const int gk = chunk * 4 + lgrp;
        const int g  = gk / 9, k = gk - 9 * g;
        const int kyy = k / 3 - 1, kxx = k % 3 - 1;

        const uint2 rr = *(const uint2*)(rawb + ((size_t)gk * HWsz + hw) * 4);
        const float oy = __uint_as_float(rr.x << 16);
        const float ox = __uint_as_float(rr.x & 0xFFFF0000u);
        const float mraw = __uint_as_float(rr.y << 16);
        const float mv = 1.f / (1.f + __expf(-mraw));

        const float py = oy + (float)(y + kyy);
        const float px = ox + (float)(x + kxx);
        const float y0f = floorf(py), x0f = floorf(px);
        const float tyf = py - y0f, txf = px - x0f;
        const int y0 = (int)y0f, x0i = (int)x0f;
        const int y1 = y0 + 1, x1 = x0i + 1;
        const bool vy0 = (y0 >= 0) & (y0 < HH);
        const bool vy1 = (y1 >= 0) & (y1 < HH);
        const bool vx0 = (x0i >= 0) & (x0i < WW);
        const bool vx1 = (x1 >= 0) & (x1 < WW);
        const int yc0 = min(max(y0, 0), HH - 1), yc1 = min(max(y1, 0), HH - 1);
        const int xc0 = min(max(x0i, 0), WW - 1), xc1 = min(max(x1, 0), WW - 1);
        const float a0 = (1.f - tyf) * mv, a1 = tyf * mv;
        float w00 = a0 * (1.f - txf);
        float w01 = a0 * txf;
        float w10 = a1 * (1.f - txf);
        float w11 = a1 * txf;
        if (!(vy0 && vx0)) w00 = 0.f;
        if (!(vy0 && vx1)) w01 = 0.f;
        if (!(vy1 && vx0)) w10 = 0.f;
        if (!(vy1 && vx1)) w11 = 0.f;

        const ushort* pb = ftsg + (size_t)(b * 8 + g) * HWsz * 8;
        const uint4 u00 = *(const uint4*)(pb + (size_t)(yc0 * WW + xc0) * 8);
        const uint4 u01 = *(const uint4*)(pb + (size_t)(yc0 * WW + xc1) * 8);
        const uint4 u10 = *(const uint4*)(pb + (size_t)(yc1 * WW + xc0) * 8);
        const uint4 u11 = *(const uint4*)(pb + (size_t)(yc1 * WW + xc1) * 8);
        float f00[8], f01[8], f10[8], f11[8];
        unpk8(u00, f00); unpk8(u01, f01); unpk8(u10, f10); unpk8(u11, f11);

        float s[8];
#pragma unroll
        for (int c = 0; c < 8; ++c)
            s[c] = fmaf(w11, f11[c], fmaf(w10, f10[c],
                    fmaf(w01, f01[c], w00 * f00[c])));
        uint4 bpk;
        asm("v_cvt_pk_bf16_f32 %0, %1, %2" : "=v"(bpk.x) : "v"(s[0]), "v"(s[1]));
        asm("v_cvt_pk_bf16_f32 %0, %1, %2" : "=v"(bpk.y) : "v"(s[2]), "v"(s[3]));
        asm("v_cvt_pk_bf16_f32 %0, %1, %2" : "=v"(bpk.z) : "v"(s[4]), "v"(s[5]));
        asm("v_cvt_pk_bf16_f32 %0, %1, %2" : "=v"(bpk.w) : "v"(s[6]), "v"(s[7]));
        const bf16x8 bfrag = __builtin_bit_cast(bf16x8, bpk);

#pragma unroll
        for (int mt = 0; mt < 4; ++mt) {
            const bf16x8 a = *(const bf16x8*)&wmp4[(size_t)(chunk * 4 + mt) * 64 + lane];
            acc[mt] = __builtin_amdgcn_mfma_f32_16x16x32_bf16(a, bfrag, acc[mt], 0, 0, 0);
        }
    }

    float* ob = out + (size_t)fidx * 64 * HWsz + hw;
#pragma unroll
    for (int mt = 0; mt < 4; ++mt) {
        const int o0 = mt * 16 + lgrp * 4;
        const float4 bs = *(const float4*)&db[o0];
        ob[(size_t)(o0 + 0) * HWsz] = acc[mt][0] + bs.x;
        ob[(size_t)(o0 + 1) * HWsz] = acc[mt][1] + bs.y;
        ob[(size_t)(o0 + 2) * HWsz] = acc[mt][2] + bs.z;
        ob[(size_t)(o0 + 3) * HWsz] = acc[mt][3] + bs.w;
    }
}

extern "C" void kernel_launch(void* const* d_in, const int* in_sizes, int n_in,
                              void* d_out, int out_size, void* d_ws, size_t ws_size,
                              hipStream_t stream)
{
    const float* x   = (const float*)d_in[0];
    const float* fw1 = (const float*)d_in[1];
    const float* fb1 = (const float*)d_in[2];
    const float* fw2 = (const float*)d_in[3];
    const float* fb2 = (const float*)d_in[4];
    const float* fw3 = (const float*)d_in[5];
    const float* fb3 = (const float*)d_in[6];
    const float* ow1 = (const float*)d_in[7];
    const float* ob1 = (const float*)d_in[8];
    const float* ow2 = (const float*)d_in[9];
    const float* ob2 = (const float*)d_in[10];
    const float* ow3 = (const float*)d_in[11];
    const float* ob3 = (const float*)d_in[12];
    const float* dw  = (const float*)d_in[13];
    const float* db  = (const float*)d_in[14];
    float* out = (float*)d_out;

    // ---- workspace layout ----
    ushort* buf1 = (ushort*)d_ws;                     // 5*HW*64 bf16
    ushort* buf2 = buf1 + (size_t)5 * HWsz * 64;
    ushort* fts  = buf2 + (size_t)5 * HWsz * 64;
    ushort* ftsg = fts + (size_t)5 * HWsz * 64;       // 4*8*HW*8 bf16
    ushort* raw  = ftsg + (size_t)4 * 8 * HWsz * 8;   // 4*72*HW*4 bf16 (packed)
    ushort* w2p  = raw + (size_t)4 * 72 * HWsz * 4;
    ushort* w3p  = w2p + 36864;
    ushort* o1p  = w3p + 36864;
    ushort* o2p  = o1p + 73728;
    ushort* o3p  = o2p + 36864;
    ushort* wmp  = o3p + 147456;                      // 18*4*64*8 bf16

    const dim3 blk(256);

    // ---- weight packing (1 launch) ----
    pack_all<<<dim3(72, 6), blk, 0, stream>>>(fw2, fw3, ow1, ow2, ow3, dw,
                                              w2p, w3p, o1p, o2p, o3p, wmp);

    // ---- feature extraction ----
    conv1_kernel<<<dim3(10, 10, 5), blk, 0, stream>>>(x, fw1, fb1, buf1);
    mfma_conv<2, 1, false, true, 0><<<dim3(5, 20, 5), blk, 0, stream>>>(
        buf1, w2p, fb2, buf2, 64, 4, 1, nullptr, nullptr);
    // conv3: writes fts NHWC + out frame 2 (f32 CHW) + ftsg group-major
    mfma_conv<2, 1, false, true, 1><<<dim3(5, 20, 5), blk, 0, stream>>>(
        buf2, w3p, fb3, fts, 64, 4, 1, out, ftsg);

    // ---- offset network ----
    mfma_conv<2, 2, true, true, 0><<<dim3(5, 20, 4), blk, 0, stream>>>(
        fts, o1p, ob1, buf1, 64, 4, 1, nullptr, nullptr);
    mfma_conv<2, 1, false, true, 0><<<dim3(5, 20, 4), blk, 0, stream>>>(
        buf1, o2p, ob2, buf2, 64, 4, 1, nullptr, nullptr);
    // ow3: writes packed bf16 raw {oy,ox,m,pad} per (gk,px)
    mfma_conv<2, 1, false, false, 3><<<dim3(5, 20, 16), blk, 0, stream>>>(
        buf2, o3p, ob3, raw, 216, 16, 4, nullptr, nullptr);

    // ---- modulated deformable conv + assembly ----
    mdcn_mfma<<<dim3(10, 40, 4), blk, 0, stream>>>(ftsg, raw, wmp, db, out);
}

// Round 7
// 197.752 us; speedup vs baseline: 15.9467x; 1.0951x over previous
//
#include <hip/hip_runtime.h>
#include <hip/hip_bf16.h>
#include <math.h>

#define HH 160
#define WW 160
#define HWsz (HH*WW)

typedef short bf16x8 __attribute__((ext_vector_type(8)));
typedef float f32x4  __attribute__((ext_vector_type(4)));

__device__ inline ushort f2bf(float f) {
    unsigned int u = __float_as_uint(f);
    unsigned int r = (u + 0x7FFFu + ((u >> 16) & 1u)) >> 16;
    return (ushort)r;
}

__device__ inline void unpk8(uint4 u, float* f) {
    f[0] = __uint_as_float(u.x << 16); f[1] = __uint_as_float(u.x & 0xFFFF0000u);
    f[2] = __uint_as_float(u.y << 16); f[3] = __uint_as_float(u.y & 0xFFFF0000u);
    f[4] = __uint_as_float(u.z << 16); f[5] = __uint_as_float(u.z & 0xFFFF0000u);
    f[6] = __uint_as_float(u.w << 16); f[7] = __uint_as_float(u.w & 0xFFFF0000u);
}

// ---------------------------------------------------------------------------
// ALL weight packing in one launch (unchanged from round 6).
// ---------------------------------------------------------------------------
__global__ __launch_bounds__(256)
void pack_all(const float* __restrict__ fw2, const float* __restrict__ fw3,
              const float* __restrict__ ow1, const float* __restrict__ ow2,
              const float* __restrict__ ow3, const float* __restrict__ dw,
              ushort* __restrict__ w2p, ushort* __restrict__ w3p,
              ushort* __restrict__ o1p, ushort* __restrict__ o2p,
              ushort* __restrict__ o3p, ushort* __restrict__ wmp)
{
    const int seg = blockIdx.y;
    const int idx = blockIdx.x * 256 + threadIdx.x;

    if (seg == 5) {   // mdcn weights
        if (idx >= 18 * 4 * 64) return;
        const int lane = idx & 63;
        const int mt   = (idx >> 6) & 3;
        const int chunk = idx >> 8;
        const int o  = mt * 16 + (lane & 15);
        const int gk = chunk * 4 + (lane >> 4);
        const int g  = gk / 9, k = gk % 9;
        ushort v[8];
#pragma unroll
        for (int j = 0; j < 8; ++j)
            v[j] = f2bf(dw[((size_t)o * 64 + g * 8 + j) * 9 + k]);
        uint4 pk;
        pk.x = (unsigned)v[0] | ((unsigned)v[1] << 16);
        pk.y = (unsigned)v[2] | ((unsigned)v[3] << 16);
        pk.z = (unsigned)v[4] | ((unsigned)v[5] << 16);
        pk.w = (unsigned)v[6] | ((unsigned)v[7] << 16);
        *(uint4*)(wmp + (size_t)idx * 8) = pk;
        return;
    }

    const float* w; ushort* wp; int Cout, Cin, MT_TOT, CIC;
    switch (seg) {
        case 0: w = fw2; wp = w2p; Cout = 64;  Cin = 64;  MT_TOT = 4;  CIC = 2; break;
        case 1: w = fw3; wp = w3p; Cout = 64;  Cin = 64;  MT_TOT = 4;  CIC = 2; break;
        case 2: w = ow1; wp = o1p; Cout = 64;  Cin = 128; MT_TOT = 4;  CIC = 4; break;
        case 3: w = ow2; wp = o2p; Cout = 64;  Cin = 64;  MT_TOT = 4;  CIC = 2; break;
        default: w = ow3; wp = o3p; Cout = 216; Cin = 64; MT_TOT = 16; CIC = 2; break;
    }
    const int total = 9 * CIC * MT_TOT * 64;
    if (idx >= total) return;
    const int lane = idx & 63;
    int t = idx >> 6;
    const int mt  = t % MT_TOT; t /= MT_TOT;
    const int cic = t % CIC;    t /= CIC;
    const int tap = t;
    const int co  = mt * 16 + (lane & 15);
    const int ci0 = cic * 32 + (lane >> 4) * 8;
    ushort v[8];
#pragma unroll
    for (int j = 0; j < 8; ++j) {
        const int ci = ci0 + j;
        float f = 0.f;
        if (co < Cout && ci < Cin) f = w[((size_t)co * Cin + ci) * 9 + tap];
        v[j] = f2bf(f);
    }
    uint4 pk;
    pk.x = (unsigned)v[0] | ((unsigned)v[1] << 16);
    pk.y = (unsigned)v[2] | ((unsigned)v[3] << 16);
    pk.z = (unsigned)v[4] | ((unsigned)v[5] << 16);
    pk.w = (unsigned)v[6] | ((unsigned)v[7] << 16);
    *(uint4*)(wp + (size_t)idx * 8) = pk;
}

// ---------------------------------------------------------------------------
// MFMA implicit-GEMM 3x3 conv, A-fragments staged in LDS per half-K.
// Block 256 thr = 4 waves; block tile 64co x (8 rows x 32) px; wave tile
// 64co x 64px. LDS: input halo tile (43.5 KB) + A half-K buffer (36 KB)
// -> 2 blocks/CU. K-loop is pure LDS+MFMA; 4 barriers per step.
// OMODE: 0 = bf16 NHWC; 1 = +fused ref-copy/ftsg-repack;
//        3 = split raw: offsets uint (outv) + masks ushort (aux).
// ---------------------------------------------------------------------------
template<int CI_STEPS, bool CONCAT, bool RELU, int OMODE>
__global__ __launch_bounds__(256, 2)
void mfma_conv(const ushort* __restrict__ in, const ushort* __restrict__ wp,
               const float* __restrict__ bias, void* __restrict__ outv,
               int Cout, int MT_TOT, int COG,
               float* __restrict__ outmain, ushort* __restrict__ aux)
{
    constexpr int ROWS = 8, HR = ROWS + 2, NT = 4;
    constexpr int C8   = 8;                  // 16B records per px per step
    constexpr int CICT = 2 * CI_STEPS;       // 32-ci chunks total
    constexpr int CIN  = CICT * 32;
    __shared__ uint4 s_in4[HR * 34 * C8];    // 43520 B
    __shared__ uint4 s_a4[9 * 4 * 64];       // 36864 B (half-K A-frags)

    const int tid = threadIdx.x;
    const int lane = tid & 63, wid = tid >> 6;
    const int lane15 = lane & 15, lgrp = lane >> 4;
    const int bz = blockIdx.z;
    const int frame = bz / COG, cog = bz % COG;
    const int x0 = blockIdx.x * 32, y0 = blockIdx.y * ROWS;

    const ushort* src = nullptr; const ushort* srcRef = nullptr; const ushort* srcCur = nullptr;
    if (CONCAT) {
        const int fidx = (frame < 2) ? frame : frame + 1;
        srcRef = in + (size_t)2 * HWsz * 64;
        srcCur = in + (size_t)fidx * HWsz * 64;
    } else {
        src = in + (size_t)frame * HWsz * CIN;
    }

    f32x4 acc[4][NT];
#pragma unroll
    for (int m = 0; m < 4; ++m)
#pragma unroll
        for (int n = 0; n < NT; ++n) acc[m][n] = (f32x4){0.f, 0.f, 0.f, 0.f};

    const uint4* wp4 = (const uint4*)wp;
    const int wrow = wid * 2;
    const int mtg0 = cog * 4;

#pragma unroll
    for (int step = 0; step < CI_STEPS; ++step) {
#pragma unroll
        for (int half = 0; half < 2; ++half) {
            // ---- stage input tile (first half of each step only) ----
            if (half == 0) {
                for (int i = tid; i < HR * 34 * C8; i += 256) {
                    const int ci8l = i & (C8 - 1);
                    const int rem = i / C8;
                    const int col = rem % 34, row = rem / 34;
                    const int gy = y0 + row - 1, gx = x0 + col - 1;
                    const int gci8 = step * C8 + ci8l;
                    uint4 v = {0u, 0u, 0u, 0u};
                    if (gy >= 0 && gy < HH && gx >= 0 && gx < WW) {
                        if (CONCAT) {
                            const ushort* sp = (gci8 < 8) ? srcRef : srcCur;
                            v = *(const uint4*)(sp + (size_t)(gy * WW + gx) * 64 + (gci8 & 7) * 8);
                        } else {
                            v = *(const uint4*)(src + (size_t)(gy * WW + gx) * CIN + gci8 * 8);
                        }
                    }
                    s_in4[(row * 34 + col) * C8 + (ci8l ^ (col & 7))] = v;
                }
            }
            // ---- stage A-fragments for this half-K (9 chunks, 36 KB) ----
#pragma unroll
            for (int it = 0; it < 9; ++it) {
                const int i = tid + it * 256;
                const int ln = i & 63, mt = (i >> 6) & 3, kkl = i >> 8;
                const int kkg = half * 9 + kkl;
                const int tap = kkg >> 1, cic = kkg & 1;
                s_a4[i] = wp4[((size_t)(tap * CICT + step * 2 + cic) * MT_TOT + mtg0 + mt) * 64 + ln];
            }
            __syncthreads();

            // ---- pure LDS+MFMA half-K loop ----
#pragma unroll
            for (int kkl = 0; kkl < 9; ++kkl) {
                const int kkg = half * 9 + kkl;
                const int tap = kkg >> 1, cic = kkg & 1;
                const int dy  = tap / 3 - 1;
                const int dxp = tap % 3;
                bf16x8 a[4];
#pragma unroll
                for (int mt = 0; mt < 4; ++mt)
                    a[mt] = *(const bf16x8*)&s_a4[(kkl * 4 + mt) * 64 + lane];
#pragma unroll
                for (int nt = 0; nt < NT; ++nt) {
                    const int row_l = wrow + (nt >> 1) + dy + 1;
                    const int col_l = (nt & 1) * 16 + lane15 + dxp;
                    const bf16x8 b = *(const bf16x8*)
                        &s_in4[(row_l * 34 + col_l) * C8 + ((cic * 4 + lgrp) ^ (col_l & 7))];
#pragma unroll
                    for (int mt = 0; mt < 4; ++mt)
                        acc[mt][nt] = __builtin_amdgcn_mfma_f32_16x16x32_bf16(a[mt], b, acc[mt][nt], 0, 0, 0);
                }
            }
            __syncthreads();
        }
    }

    // ---- epilogue ----
#pragma unroll
    for (int mt = 0; mt < 4; ++mt) {
        const int co = cog * 64 + mt * 16 + lgrp * 4;
        if (co < Cout) {
            const float4 bs = *(const float4*)&bias[co];
#pragma unroll
            for (int nt = 0; nt < NT; ++nt) {
                const int yy = y0 + wrow + (nt >> 1);
                const int xx = x0 + (nt & 1) * 16 + lane15;
                const int hw = yy * WW + xx;
                f32x4 v = acc[mt][nt];
                v[0] += bs.x; v[1] += bs.y; v[2] += bs.z; v[3] += bs.w;
                if (RELU) {
                    v[0] = fmaxf(v[0], 0.f); v[1] = fmaxf(v[1], 0.f);
                    v[2] = fmaxf(v[2], 0.f); v[3] = fmaxf(v[3], 0.f);
                }
                if (OMODE <= 1) {
                    uint2 pk;
                    pk.x = (unsigned)f2bf(v[0]) | ((unsigned)f2bf(v[1]) << 16);
                    pk.y = (unsigned)f2bf(v[2]) | ((unsigned)f2bf(v[3]) << 16);
                    *(uint2*)((ushort*)outv + ((size_t)frame * HWsz + hw) * 64 + co) = pk;
                    if (OMODE == 1) {
                        if (frame == 2) {
#pragma unroll
                            for (int j = 0; j < 4; ++j)
                                outmain[((size_t)(128 + co + j)) * HWsz + hw] = v[j];
                        } else {
                            const int b = (frame < 2) ? frame : frame - 1;
                            *(uint2*)(aux + (((size_t)(b * 8 + (co >> 3)) * HWsz + hw) * 8 + (co & 7))) = pk;
                        }
                    }
                } else {
                    // OMODE==3: offsets -> uint roff[gk][px], masks -> ushort rmsk[gk][px]
                    const ushort h0 = f2bf(v[0]), h1 = f2bf(v[1]);
                    const ushort h2 = f2bf(v[2]), h3 = f2bf(v[3]);
                    if (co < 144) {
                        unsigned* roff = (unsigned*)outv + (size_t)frame * 72 * HWsz;
                        roff[(size_t)(co >> 1) * HWsz + hw]       = (unsigned)h0 | ((unsigned)h1 << 16);
                        roff[(size_t)((co >> 1) + 1) * HWsz + hw] = (unsigned)h2 | ((unsigned)h3 << 16);
                    } else {
                        ushort* rmsk = aux + (size_t)frame * 72 * HWsz;
                        const int gk0 = co - 144;
                        rmsk[(size_t)(gk0 + 0) * HWsz + hw] = h0;
                        rmsk[(size_t)(gk0 + 1) * HWsz + hw] = h1;
                        rmsk[(size_t)(gk0 + 2) * HWsz + hw] = h2;
                        rmsk[(size_t)(gk0 + 3) * HWsz + hw] = h3;
                    }
                }
            }
        }
    }
}

// ---------------------------------------------------------------------------
// conv1: Cin=4 NCHW f32 -> 64ch NHWC bf16 (unchanged).
// ---------------------------------------------------------------------------
__global__ __launch_bounds__(256)
void conv1_kernel(const float* __restrict__ x, const float* __restrict__ w,
                  const float* __restrict__ b, ushort* __restrict__ out)
{
    const int fr = blockIdx.z;
    const int t = threadIdx.x;
    const int tx = t & 15, ty = t >> 4;
    const int x0 = blockIdx.x * 16, y0 = blockIdx.y * 16;

    __shared__ float s_x[4][18][18];
    __shared__ float s_w[36][64];
    __shared__ float s_b[64];

    for (int i = t; i < 4 * 18 * 18; i += 256) {
        const int ci = i / 324, rem = i % 324;
        const int yy = rem / 18, xx = rem % 18;
        const int gy = y0 + yy - 1, gx = x0 + xx - 1;
        float v = 0.f;
        if (gy >= 0 && gy < HH && gx >= 0 && gx < WW)
            v = x[((size_t)fr * 4 + ci) * HWsz + gy * WW + gx];
        s_x[ci][yy][xx] = v;
    }
    for (int i = t; i < 36 * 64; i += 256) {
        const int row = i / 64, o = i % 64;
        const int ci = row / 9, tap = row % 9;
        s_w[row][o] = w[((size_t)o * 4 + ci) * 9 + tap];
    }
    if (t < 64) s_b[t] = b[t];
    __syncthreads();

    float acc[64];
#pragma unroll
    for (int i = 0; i < 64; ++i) acc[i] = 0.f;

#pragma unroll
    for (int ci = 0; ci < 4; ++ci) {
#pragma unroll
        for (int tap = 0; tap < 9; ++tap) {
            const float v = s_x[ci][ty + tap / 3][tx + tap % 3];
            const float4* wr = (const float4*)&s_w[ci * 9 + tap][0];
#pragma unroll
            for (int o4 = 0; o4 < 16; ++o4) {
                const float4 wv = wr[o4];
                acc[o4 * 4 + 0] = fmaf(v, wv.x, acc[o4 * 4 + 0]);
                acc[o4 * 4 + 1] = fmaf(v, wv.y, acc[o4 * 4 + 1]);
                acc[o4 * 4 + 2] = fmaf(v, wv.z, acc[o4 * 4 + 2]);
                acc[o4 * 4 + 3] = fmaf(v, wv.w, acc[o4 * 4 + 3]);
            }
        }
    }

    ushort* ob = out + ((size_t)fr * HWsz + (y0 + ty) * WW + (x0 + tx)) * 64;
#pragma unroll
    for (int o8 = 0; o8 < 8; ++o8) {
        ushort v[8];
#pragma unroll
        for (int j = 0; j < 8; ++j)
            v[j] = f2bf(fmaxf(acc[o8 * 8 + j] + s_b[o8 * 8 + j], 0.f));
        uint4 pk;
        pk.x = (unsigned)v[0] | ((unsigned)v[1] << 16);
        pk.y = (unsigned)v[2] | ((unsigned)v[3] << 16);
        pk.z = (unsigned)v[4] | ((unsigned)v[5] << 16);
        pk.w = (unsigned)v[6] | ((unsigned)v[7] << 16);
        *(uint4*)(ob + o8 * 8) = pk;
    }
}

// ---------------------------------------------------------------------------
// MDCN MFMA GEMM: split raw buffers (uint offsets + ushort masks).
// ---------------------------------------------------------------------------
__global__ __launch_bounds__(256)
void mdcn_mfma(const ushort* __restrict__ ftsg, const unsigned* __restrict__ roffg,
               const ushort* __restrict__ rmskg,
               const ushort* __restrict__ wmp, const float* __restrict__ db,
               float* __restrict__ out)
{
    const int b    = blockIdx.z;
    const int fidx = (b < 2) ? b : b + 1;
    const int tid  = threadIdx.x;
    const int lane = tid & 63, wid = tid >> 6;
    const int lane15 = lane & 15, lgrp = lane >> 4;
    const int x = blockIdx.x * 16 + lane15;
    const int y = blockIdx.y * 4 + wid;
    const int hw = y * WW + x;

    const unsigned* roff = roffg + (size_t)b * 72 * HWsz;
    const ushort*   rmsk = rmskg + (size_t)b * 72 * HWsz;
    const uint4* wmp4 = (const uint4*)wmp;

    f32x4 acc[4];
#pragma unroll
    for (int m = 0; m < 4; ++m) acc[m] = (f32x4){0.f, 0.f, 0.f, 0.f};

#pragma unroll 2
    for (int chunk = 0; chunk < 18; ++chunk) {
        const int gk = chunk * 4 + lgrp;
        const int g  = gk / 9, k = gk - 9 * g;
        const int kyy = k / 3 - 1, kxx = k % 3 - 1;

        const unsigned op = roff[(size_t)gk * HWsz + hw];
        const ushort   mu = rmsk[(size_t)gk * HWsz + hw];
        const float oy = __uint_as_float(op << 16);
        const float ox = __uint_as_float(op & 0xFFFF0000u);
        const float mraw = __uint_as_float((unsigned)mu << 16);
        const float mv = 1.f / (1.f + __expf(-mraw));

        const float py = oy + (float)(y + kyy);
        const float px = ox + (float)(x + kxx);
        const float y0f = floorf(py), x0f = floorf(px);
        const float tyf = py - y0f, txf = px - x0f;
        const int y0 = (int)y0f, x0i = (int)x0f;
        const int y1 = y0 + 1, x1 = x0i + 1;
        const bool vy0 = (y0 >= 0) & (y0 < HH);
        const bool vy1 = (y1 >= 0) & (y1 < HH);
        const bool vx0 = (x0i >= 0) & (x0i < WW);
        const bool vx1 = (x1 >= 0) & (x1 < WW);
        const int yc0 = min(max(y0, 0), HH - 1), yc1 = min(max(y1, 0), HH - 1);
        const int xc0 = min(max(x0i, 0), WW - 1), xc1 = min(max(x1, 0), WW - 1);
        const float a0 = (1.f - tyf) * mv, a1 = tyf * mv;
        float w00 = a0 * (1.f - txf);
        float w01 = a0 * txf;
        float w10 = a1 * (1.f - txf);
        float w11 = a1 * txf;
        if (!(vy0 && vx0)) w00 = 0.f;
        if (!(vy0 && vx1)) w01 = 0.f;
        if (!(vy1 && vx0)) w10 = 0.f;
        if (!(vy1 && vx1)) w11 = 0.f;

        const ushort* pb = ftsg + (size_t)(b * 8 + g) * HWsz * 8;
        const uint4 u00 = *(const uint4*)(pb + (size_t)(yc0 * WW + xc0) * 8);
        const uint4 u01 = *(const uint4*)(pb + (size_t)(yc0 * WW + xc1) * 8);
        const uint4 u10 = *(const uint4*)(pb + (size_t)(yc1 * WW + xc0) * 8);
        const uint4 u11 = *(const uint4*)(pb + (size_t)(yc1 * WW + xc1) * 8);
        float f00[8], f01[8], f10[8], f11[8];
        unpk8(u00, f00); unpk8(u01, f01); unpk8(u10, f10); unpk8(u11, f11);

        float s[8];
#pragma unroll
        for (int c = 0; c < 8; ++c)
            s[c] = fmaf(w11, f11[c], fmaf(w10, f10[c],
                    fmaf(w01, f01[c], w00 * f00[c])));
        uint4 bpk;
        asm("v_cvt_pk_bf16_f32 %0, %1, %2" : "=v"(bpk.x) : "v"(s[0]), "v"(s[1]));
        asm("v_cvt_pk_bf16_f32 %0, %1, %2" : "=v"(bpk.y) : "v"(s[2]), "v"(s[3]));
        asm("v_cvt_pk_bf16_f32 %0, %1, %2" : "=v"(bpk.z) : "v"(s[4]), "v"(s[5]));
        asm("v_cvt_pk_bf16_f32 %0, %1, %2" : "=v"(bpk.w) : "v"(s[6]), "v"(s[7]));
        const bf16x8 bfrag = __builtin_bit_cast(bf16x8, bpk);

#pragma unroll
        for (int mt = 0; mt < 4; ++mt) {
            const bf16x8 a = *(const bf16x8*)&wmp4[(size_t)(chunk * 4 + mt) * 64 + lane];
            acc[mt] = __builtin_amdgcn_mfma_f32_16x16x32_bf16(a, bfrag, acc[mt], 0, 0, 0);
        }
    }

    float* ob = out + (size_t)fidx * 64 * HWsz + hw;
#pragma unroll
    for (int mt = 0; mt < 4; ++mt) {
        const int o0 = mt * 16 + lgrp * 4;
        const float4 bs = *(const float4*)&db[o0];
        ob[(size_t)(o0 + 0) * HWsz] = acc[mt][0] + bs.x;
        ob[(size_t)(o0 + 1) * HWsz] = acc[mt][1] + bs.y;
        ob[(size_t)(o0 + 2) * HWsz] = acc[mt][2] + bs.z;
        ob[(size_t)(o0 + 3) * HWsz] = acc[mt][3] + bs.w;
    }
}

extern "C" void kernel_launch(void* const* d_in, const int* in_sizes, int n_in,
                              void* d_out, int out_size, void* d_ws, size_t ws_size,
                              hipStream_t stream)
{
    const float* x   = (const float*)d_in[0];
    const float* fw1 = (const float*)d_in[1];
    const float* fb1 = (const float*)d_in[2];
    const float* fw2 = (const float*)d_in[3];
    const float* fb2 = (const float*)d_in[4];
    const float* fw3 = (const float*)d_in[5];
    const float* fb3 = (const float*)d_in[6];
    const float* ow1 = (const float*)d_in[7];
    const float* ob1 = (const float*)d_in[8];
    const float* ow2 = (const float*)d_in[9];
    const float* ob2 = (const float*)d_in[10];
    const float* ow3 = (const float*)d_in[11];
    const float* ob3 = (const float*)d_in[12];
    const float* dw  = (const float*)d_in[13];
    const float* db  = (const float*)d_in[14];
    float* out = (float*)d_out;

    // ---- workspace layout (ushort units) ----
    ushort* buf1 = (ushort*)d_ws;                     // 5*HW*64
    ushort* buf2 = buf1 + (size_t)5 * HWsz * 64;
    ushort* fts  = buf2 + (size_t)5 * HWsz * 64;
    ushort* ftsg = fts + (size_t)5 * HWsz * 64;       // 4*8*HW*8
    unsigned* roff = (unsigned*)(ftsg + (size_t)4 * 8 * HWsz * 8);  // 4*72*HW uint
    ushort* rmsk = (ushort*)(roff + (size_t)4 * 72 * HWsz);         // 4*72*HW ushort
    ushort* w2p  = rmsk + (size_t)4 * 72 * HWsz;
    ushort* w3p  = w2p + 36864;
    ushort* o1p  = w3p + 36864;
    ushort* o2p  = o1p + 73728;
    ushort* o3p  = o2p + 36864;
    ushort* wmp  = o3p + 147456;

    const dim3 blk(256);

    // ---- weight packing ----
    pack_all<<<dim3(72, 6), blk, 0, stream>>>(fw2, fw3, ow1, ow2, ow3, dw,
                                              w2p, w3p, o1p, o2p, o3p, wmp);

    // ---- feature extraction ----
    conv1_kernel<<<dim3(10, 10, 5), blk, 0, stream>>>(x, fw1, fb1, buf1);
    mfma_conv<1, false, true, 0><<<dim3(5, 20, 5), blk, 0, stream>>>(
        buf1, w2p, fb2, buf2, 64, 4, 1, nullptr, nullptr);
    // conv3: writes fts NHWC + out frame 2 (f32 CHW) + ftsg group-major
    mfma_conv<1, false, true, 1><<<dim3(5, 20, 5), blk, 0, stream>>>(
        buf2, w3p, fb3, fts, 64, 4, 1, out, ftsg);

    // ---- offset network ----
    mfma_conv<2, true, true, 0><<<dim3(5, 20, 4), blk, 0, stream>>>(
        fts, o1p, ob1, buf1, 64, 4, 1, nullptr, nullptr);
    mfma_conv<1, false, true, 0><<<dim3(5, 20, 4), blk, 0, stream>>>(
        buf1, o2p, ob2, buf2, 64, 4, 1, nullptr, nullptr);
    // ow3: split raw writes (offsets uint + masks ushort)
    mfma_conv<1, false, false, 3><<<dim3(5, 20, 16), blk, 0, stream>>>(
        buf2, o3p, ob3, roff, 216, 16, 4, nullptr, rmsk);

    // ---- modulated deformable conv + assembly ----
    mdcn_mfma<<<dim3(10, 40, 4), blk, 0, stream>>>(ftsg, roff, rmsk, wmp, db, out);
}